// Round 5
// baseline (192.808 us; speedup 1.0000x reference)
//
#include <hip/hip_runtime.h>
#include <stdint.h>

typedef __attribute__((ext_vector_type(8))) short short8;
typedef __attribute__((ext_vector_type(4))) float f32x4;
typedef __attribute__((ext_vector_type(16))) float f32x16;
typedef __attribute__((ext_vector_type(4))) unsigned short ushort4v;
typedef __attribute__((ext_vector_type(2))) int int2v;

#define BB 2
#define SS 2048
#define NXDIM 1024
#define NHEADS 16
#define HDIM 64

__device__ __forceinline__ unsigned short f2bf(float f){
  unsigned int u = __float_as_uint(f);
  u += 0x7fffu + ((u >> 16) & 1u);
  return (unsigned short)(u >> 16);
}

__device__ __forceinline__ void gload_lds16(const void* g, void* l){
  __builtin_amdgcn_global_load_lds((const __attribute__((address_space(1))) void*)g,
                                   (__attribute__((address_space(3))) void*)l, 16, 0, 0);
}

__device__ __forceinline__ unsigned cvt_pk_bf16(float lo, float hi){
  unsigned r;
  asm("v_cvt_pk_bf16_f32 %0, %1, %2" : "=v"(r) : "v"(lo), "v"(hi));
  return r;
}

__device__ __forceinline__ int2v ds_tr_b16(unsigned addr){
  int2v r;
  asm volatile("ds_read_b64_tr_b16 %0, %1" : "=v"(r) : "v"(addr));
  return r;
}

// ---------------- f32 -> bf16 convert (vectorized) ----------------
__global__ __launch_bounds__(256) void f32_to_bf16_k(const float* __restrict__ in,
                                                     unsigned short* __restrict__ out, int n4){
  int i = blockIdx.x * 256 + threadIdx.x;
  if (i >= n4) return;
  float4 v = ((const float4*)in)[i];
  ushort4v r = { f2bf(v.x), f2bf(v.y), f2bf(v.z), f2bf(v.w) };
  ((ushort4v*)out)[i] = r;
}

// ---------------- f32 [R][C] -> bf16 transposed [C][R] ----------------
__global__ __launch_bounds__(256) void transpose_bf16_k(const float* __restrict__ in,
                                                        unsigned short* __restrict__ out,
                                                        int R, int C){
  __shared__ float t[32][33];
  const int bx = blockIdx.x * 32, by = blockIdx.y * 32;
  const int tx = threadIdx.x, ty = threadIdx.y;
  #pragma unroll
  for (int i = ty; i < 32; i += 8)
    t[i][tx] = in[(size_t)(by + i) * C + bx + tx];
  __syncthreads();
  #pragma unroll
  for (int i = ty; i < 32; i += 8)
    out[(size_t)(bx + i) * R + by + tx] = f2bf(t[tx][i]);
}

// ---------------- bf16 GEMM: C[M,N] = A[M,K] * BT[N,K]^T + bias ----------------
template<bool OUT_F32>
__global__ __launch_bounds__(256) void gemm_bt_k(const unsigned short* __restrict__ A,
                                                 const unsigned short* __restrict__ BT,
                                                 const float* __restrict__ bias,
                                                 void* __restrict__ Cout,
                                                 int M, int N, int K)
{
  __shared__ unsigned short As[128*32];
  __shared__ unsigned short Bs[128*32];
  const int tid = threadIdx.x;
  const int w = tid >> 6, lane = tid & 63;
  const int l15 = lane & 15, g = lane >> 4;
  const int wr = w >> 1, wc = w & 1;
  const int m0 = blockIdx.y * 128, n0 = blockIdx.x * 128;

  f32x4 acc[4][4];
  #pragma unroll
  for (int m=0;m<4;m++)
    #pragma unroll
    for (int n=0;n<4;n++) acc[m][n] = (f32x4){0.f,0.f,0.f,0.f};

  const int scol = (lane & 3) * 8;

  for (int k0 = 0; k0 < K; k0 += 32){
    __syncthreads();
    #pragma unroll
    for (int j=0;j<2;j++){
      const int row = w*32 + j*16 + (lane >> 2);
      const unsigned short* ga = A  + (size_t)(m0 + row) * K + (k0 + scol);
      const unsigned short* gb = BT + (size_t)(n0 + row) * K + (k0 + scol);
      gload_lds16(ga, &As[(w*32 + j*16) * 32]);
      gload_lds16(gb, &Bs[(w*32 + j*16) * 32]);
    }
    __syncthreads();

    short8 af[4], bf[4];
    #pragma unroll
    for (int m=0;m<4;m++) af[m] = *(const short8*)&As[(wr*64 + m*16 + l15)*32 + g*8];
    #pragma unroll
    for (int n=0;n<4;n++) bf[n] = *(const short8*)&Bs[(wc*64 + n*16 + l15)*32 + g*8];
    #pragma unroll
    for (int m=0;m<4;m++)
      #pragma unroll
      for (int n=0;n<4;n++)
        acc[m][n] = __builtin_amdgcn_mfma_f32_16x16x32_bf16(af[m], bf[n], acc[m][n], 0, 0, 0);
  }

  const int crow0 = m0 + wr*64;
  const int ccol0 = n0 + wc*64;
  #pragma unroll
  for (int n=0;n<4;n++){
    const int col = ccol0 + n*16 + l15;
    const float bv = bias[col];
    #pragma unroll
    for (int m=0;m<4;m++){
      #pragma unroll
      for (int r=0;r<4;r++){
        const int row = crow0 + m*16 + g*4 + r;
        const float v = acc[m][n][r] + bv;
        if (OUT_F32) ((float*)Cout)[(size_t)row * N + col] = v;
        else         ((unsigned short*)Cout)[(size_t)row * N + col] = f2bf(v);
      }
    }
  }
}

// ---------------- causal flash attention, swapped-operand 32x32 MFMA ----------------
// 256 threads = 4 waves. QBLK=64. Wave w: qhalf=w>>1 owns q rows [qb*64+qhalf*32,+32),
// parity p=w&1 processes KV tiles t with t&1==p (independent online-softmax partial).
// Buffer p holds parity-p tiles. End: LDS merge of the two parity partials per q-half.
// S^T = mfma(K, Q^T): col=q(lane&31), row=kv((r&3)+8*(r>>2)+4*hi); exp2-domain softmax.
__global__ __launch_bounds__(256) void attn_k(const unsigned short* __restrict__ qkv,
                                              unsigned short* __restrict__ aout)
{
  const int qb = (int)gridDim.x - 1 - (int)blockIdx.x;   // heavy tiles first
  const int h = blockIdx.y, b = blockIdx.z;
  const int tid = threadIdx.x;
  const int w = tid >> 6, lane = tid & 63;
  const int l31 = lane & 31, hi = lane >> 5;
  const int qhalf = w >> 1, p = w & 1;

  __shared__ unsigned short Ks[2][64*64];   // [kv][d] XOR-swizzled rows (byte ^= (row&7)<<4)
  __shared__ unsigned short Vs[2][64*64];   // subtiled for ds_read_b64_tr_b16

  const size_t rs = 3 * NXDIM;
  const unsigned short* Qg = qkv + (size_t)b * SS * rs + h * HDIM;
  const unsigned short* Kg = Qg + NXDIM;
  const unsigned short* Vg = Qg + 2 * NXDIM;

  const int q0w = qb*64 + qhalf*32;
  const int q   = q0w + l31;
  const int qw_hi = q0w + 31;

  short8 qf[4];
  #pragma unroll
  for (int c=0;c<4;c++)
    qf[c] = *(const short8*)(Qg + (size_t)q * rs + c*16 + 8*hi);

  f32x16 O0, O1;
  #pragma unroll
  for (int r=0;r<16;r++){ O0[r]=0.f; O1[r]=0.f; }
  float m_run = -1e30f, l_run = 0.f;
  const float SC2 = 0.125f * 1.44269504089f;   // scale * log2(e)

  // staging source coords (verified maps)
  const int krow_in = lane >> 3;
  const int kcol    = 8 * ((lane & 7) ^ (lane >> 3));
  const int v_d     = ((lane >> 3) & 3) * 16 + 8 * (lane & 1);
  const unsigned vtr_base = (unsigned)(size_t)&Vs[0][0] + 8u*(unsigned)lane + 768u*(unsigned)hi;

  const char* Kb = (const char*)&Ks[p][0];
  const unsigned vb = vtr_base + (unsigned)(p * 8192);

  for (int t0 = 0; t0 <= qb; t0 += 2){
    const int t = t0 + p;                  // this wave's tile (parity buffer p)
    // stage own-parity tile: waves {p, p+2} cover chunks {qhalf*4..qhalf*4+3}
    if (t <= qb){
      #pragma unroll
      for (int j=0;j<4;j++){
        const int ch = qhalf*4 + j;
        const int krow = t*64 + ch*8 + krow_in;
        gload_lds16(Kg + (size_t)krow * rs + kcol, &Ks[p][ch*512]);
        const int vkv = t*64 + (ch*2 + hi)*4 + ((lane>>1)&3);
        gload_lds16(Vg + (size_t)vkv * rs + v_d, &Vs[p][ch*512]);
      }
    }
    __syncthreads();                       // drains vmcnt -> both buffers ready

    if (t <= qb){
      #pragma unroll
      for (int kvs=0;kvs<2;kvs++){
        const int kv_lo = t*64 + kvs*32;
        if (kv_lo > qw_hi) continue;       // wave-uniform skip (fully masked)

        // ---- S^T = K * Q^T ----
        f32x16 S;
        #pragma unroll
        for (int r=0;r<16;r++) S[r] = 0.f;
        __builtin_amdgcn_s_setprio(1);
        #pragma unroll
        for (int c=0;c<4;c++){
          const int row = kvs*32 + l31;
          short8 kf = *(const short8*)(Kb + row*128 + ((c*32 + 16*hi) ^ ((row&7)<<4)));
          S = __builtin_amdgcn_mfma_f32_32x32x16_bf16(kf, qf[c], S, 0, 0, 0);
        }
        __builtin_amdgcn_s_setprio(0);

        // ---- online softmax, exp2 domain (per-lane column q) ----
        float mx = -1e30f;
        if (kv_lo + 31 > q0w){
          #pragma unroll
          for (int r=0;r<16;r++){
            const int kv = kv_lo + (r&3) + 8*(r>>2) + 4*hi;
            float sv = (kv <= q) ? S[r]*SC2 : -1e30f;
            S[r] = sv; mx = fmaxf(mx, sv);
          }
        } else {
          #pragma unroll
          for (int r=0;r<16;r++){ float sv = S[r]*SC2; S[r] = sv; mx = fmaxf(mx, sv); }
        }
        mx = fmaxf(mx, __shfl_xor(mx, 32));
        const float m_new = fmaxf(m_run, mx);
        const float corr = __builtin_exp2f(m_run - m_new);
        m_run = m_new;
        float ls = 0.f;
        #pragma unroll
        for (int r=0;r<16;r++){ const float pe = __builtin_exp2f(S[r] - m_new); S[r] = pe; ls += pe; }
        ls += __shfl_xor(ls, 32);
        l_run = l_run * corr + ls;
        #pragma unroll
        for (int r=0;r<16;r++){ O0[r] *= corr; O1[r] *= corr; }

        // ---- P^T -> bf16 fragment via cvt_pk + shfl_xor half-exchange ----
        unsigned pk[8], xk[8];
        #pragma unroll
        for (int i=0;i<8;i++) pk[i] = cvt_pk_bf16(S[2*i], S[2*i+1]);
        #pragma unroll
        for (int i=0;i<8;i++) xk[i] = (unsigned)__shfl_xor((int)pk[i], 32);
        short8 pfrag[2];
        #pragma unroll
        for (int c=0;c<2;c++){
          union { unsigned u[4]; short8 s; } pw;
          pw.u[0] = hi ? xk[4*c+2] : pk[4*c+0];
          pw.u[1] = hi ? xk[4*c+3] : pk[4*c+1];
          pw.u[2] = hi ? pk[4*c+2] : xk[4*c+0];
          pw.u[3] = hi ? pk[4*c+3] : xk[4*c+1];
          pfrag[c] = pw.s;
        }

        // ---- V^T fragments via ds_read_b64_tr_b16, then O^T += V^T * P^T ----
        int2v tv[8];
        #pragma unroll
        for (int c=0;c<2;c++)
          #pragma unroll
          for (int dh=0;dh<2;dh++)
            #pragma unroll
            for (int eb=0;eb<2;eb++)
              tv[c*4+dh*2+eb] = ds_tr_b16(vb + (unsigned)((kvs*8 + c*4 + eb)*512 + dh*256));
        asm volatile("s_waitcnt lgkmcnt(0)" ::: "memory");
        __builtin_amdgcn_sched_barrier(0);

        __builtin_amdgcn_s_setprio(1);
        #pragma unroll
        for (int c=0;c<2;c++){
          union { int2v t[2]; short8 s; } v0, v1;
          v0.t[0] = tv[c*4+0]; v0.t[1] = tv[c*4+1];
          v1.t[0] = tv[c*4+2]; v1.t[1] = tv[c*4+3];
          O0 = __builtin_amdgcn_mfma_f32_32x32x16_bf16(v0.s, pfrag[c], O0, 0, 0, 0);
          O1 = __builtin_amdgcn_mfma_f32_32x32x16_bf16(v1.s, pfrag[c], O1, 0, 0, 0);
        }
        __builtin_amdgcn_s_setprio(0);
      }
    }

    __syncthreads();                       // protect buffers before restage
  }

  // ---- merge parity partials (p=1 -> LDS, p=0 merges + writes) ----
  float* sm = qhalf ? (float*)&Vs[0][0] : (float*)&Ks[0][0];
  if (p){
    #pragma unroll
    for (int r=0;r<16;r++){ sm[lane*32 + r] = O0[r]; sm[lane*32 + 16 + r] = O1[r]; }
    sm[2048 + lane] = m_run;
    sm[2112 + lane] = l_run;
  }
  __syncthreads();
  if (!p){
    const float m1 = sm[2048 + lane], l1 = sm[2112 + lane];
    const float mm = fmaxf(m_run, m1);
    const float c0 = __builtin_exp2f(m_run - mm);
    const float c1 = __builtin_exp2f(m1 - mm);
    const float inv = 1.f / (l_run*c0 + l1*c1);
    unsigned short* dst = aout + ((size_t)b*SS + q) * NXDIM + h*HDIM;
    #pragma unroll
    for (int g4=0; g4<4; g4++){
      ushort4v a0, a1;
      #pragma unroll
      for (int i=0;i<4;i++){
        a0[i] = f2bf((O0[4*g4+i]*c0 + sm[lane*32 + 4*g4+i]*c1) * inv);
        a1[i] = f2bf((O1[4*g4+i]*c0 + sm[lane*32 + 16 + 4*g4+i]*c1) * inv);
      }
      *(ushort4v*)(dst + 8*g4 + 4*hi)      = a0;
      *(ushort4v*)(dst + 32 + 8*g4 + 4*hi) = a1;
    }
  }
}

extern "C" void kernel_launch(void* const* d_in, const int* in_sizes, int n_in,
                              void* d_out, int out_size, void* d_ws, size_t ws_size,
                              hipStream_t stream){
  (void)in_sizes; (void)n_in; (void)out_size; (void)ws_size;
  const float* x      = (const float*)d_in[0];   // [2,2048,1024]
  const float* w_attn = (const float*)d_in[1];   // [1024,3072]
  const float* b_attn = (const float*)d_in[2];   // [3072]
  const float* w_proj = (const float*)d_in[3];   // [1024,1024]
  const float* b_proj = (const float*)d_in[4];   // [1024]
  float* out = (float*)d_out;                    // [2,2048,1024] f32

  unsigned short* xb   = (unsigned short*)d_ws;              // 4096x1024 bf16
  unsigned short* waT  = xb  + (size_t)4096*1024;            // 3072x1024 bf16 (W_attn^T)
  unsigned short* wpT  = waT + (size_t)3072*1024;            // 1024x1024 bf16 (W_proj^T)
  unsigned short* qkv  = wpT + (size_t)1024*1024;            // 4096x3072 bf16
  unsigned short* aout = qkv + (size_t)4096*3072;            // 4096x1024 bf16

  f32_to_bf16_k<<<4096, 256, 0, stream>>>(x, xb, 4096*1024/4);
  transpose_bf16_k<<<dim3(3072/32, 1024/32), dim3(32,8), 0, stream>>>(w_attn, waT, 1024, 3072);
  transpose_bf16_k<<<dim3(1024/32, 1024/32), dim3(32,8), 0, stream>>>(w_proj, wpT, 1024, 1024);

  gemm_bt_k<false><<<dim3(3072/128, 4096/128), 256, 0, stream>>>(xb, waT, b_attn, (void*)qkv, 4096, 3072, 1024);
  attn_k<<<dim3(SS/64, NHEADS, BB), 256, 0, stream>>>(qkv, aout);
  gemm_bt_k<true><<<dim3(1024/128, 4096/128), 256, 0, stream>>>(aout, wpT, b_proj, (void*)out, 4096, 1024, 1024);
}

// Round 6
// 182.124 us; speedup vs baseline: 1.0587x; 1.0587x over previous
//
#include <hip/hip_runtime.h>
#include <stdint.h>

typedef __attribute__((ext_vector_type(8))) short short8;
typedef __attribute__((ext_vector_type(4))) float f32x4;
typedef __attribute__((ext_vector_type(16))) float f32x16;
typedef __attribute__((ext_vector_type(4))) unsigned short ushort4v;
typedef __attribute__((ext_vector_type(2))) int int2v;

#define BB 2
#define SS 2048
#define NXDIM 1024
#define NHEADS 16
#define HDIM 64

__device__ __forceinline__ unsigned short f2bf(float f){
  unsigned int u = __float_as_uint(f);
  u += 0x7fffu + ((u >> 16) & 1u);
  return (unsigned short)(u >> 16);
}

__device__ __forceinline__ void gload_lds16(const void* g, void* l){
  __builtin_amdgcn_global_load_lds((const __attribute__((address_space(1))) void*)g,
                                   (__attribute__((address_space(3))) void*)l, 16, 0, 0);
}

__device__ __forceinline__ unsigned cvt_pk_bf16(float lo, float hi){
  unsigned r;
  asm("v_cvt_pk_bf16_f32 %0, %1, %2" : "=v"(r) : "v"(lo), "v"(hi));
  return r;
}

__device__ __forceinline__ int2v ds_tr_b16(unsigned addr){
  int2v r;
  asm volatile("ds_read_b64_tr_b16 %0, %1" : "=v"(r) : "v"(addr));
  return r;
}

// ---------------- f32 -> bf16 convert (vectorized) ----------------
__global__ __launch_bounds__(256) void f32_to_bf16_k(const float* __restrict__ in,
                                                     unsigned short* __restrict__ out, int n4){
  int i = blockIdx.x * 256 + threadIdx.x;
  if (i >= n4) return;
  float4 v = ((const float4*)in)[i];
  ushort4v r = { f2bf(v.x), f2bf(v.y), f2bf(v.z), f2bf(v.w) };
  ((ushort4v*)out)[i] = r;
}

// ---------------- f32 [R][C] -> bf16 transposed [C][R] ----------------
__global__ __launch_bounds__(256) void transpose_bf16_k(const float* __restrict__ in,
                                                        unsigned short* __restrict__ out,
                                                        int R, int C){
  __shared__ float t[32][33];
  const int bx = blockIdx.x * 32, by = blockIdx.y * 32;
  const int tx = threadIdx.x, ty = threadIdx.y;
  #pragma unroll
  for (int i = ty; i < 32; i += 8)
    t[i][tx] = in[(size_t)(by + i) * C + bx + tx];
  __syncthreads();
  #pragma unroll
  for (int i = ty; i < 32; i += 8)
    out[(size_t)(bx + i) * R + by + tx] = f2bf(t[tx][i]);
}

// ---------------- bf16 GEMM: C[M,N] = A[M,K] * BT[N,K]^T + bias ----------------
template<bool OUT_F32>
__global__ __launch_bounds__(256) void gemm_bt_k(const unsigned short* __restrict__ A,
                                                 const unsigned short* __restrict__ BT,
                                                 const float* __restrict__ bias,
                                                 void* __restrict__ Cout,
                                                 int M, int N, int K)
{
  __shared__ unsigned short As[128*32];
  __shared__ unsigned short Bs[128*32];
  const int tid = threadIdx.x;
  const int w = tid >> 6, lane = tid & 63;
  const int l15 = lane & 15, g = lane >> 4;
  const int wr = w >> 1, wc = w & 1;
  const int m0 = blockIdx.y * 128, n0 = blockIdx.x * 128;

  f32x4 acc[4][4];
  #pragma unroll
  for (int m=0;m<4;m++)
    #pragma unroll
    for (int n=0;n<4;n++) acc[m][n] = (f32x4){0.f,0.f,0.f,0.f};

  const int scol = (lane & 3) * 8;

  for (int k0 = 0; k0 < K; k0 += 32){
    __syncthreads();
    #pragma unroll
    for (int j=0;j<2;j++){
      const int row = w*32 + j*16 + (lane >> 2);
      const unsigned short* ga = A  + (size_t)(m0 + row) * K + (k0 + scol);
      const unsigned short* gb = BT + (size_t)(n0 + row) * K + (k0 + scol);
      gload_lds16(ga, &As[(w*32 + j*16) * 32]);
      gload_lds16(gb, &Bs[(w*32 + j*16) * 32]);
    }
    __syncthreads();

    short8 af[4], bf[4];
    #pragma unroll
    for (int m=0;m<4;m++) af[m] = *(const short8*)&As[(wr*64 + m*16 + l15)*32 + g*8];
    #pragma unroll
    for (int n=0;n<4;n++) bf[n] = *(const short8*)&Bs[(wc*64 + n*16 + l15)*32 + g*8];
    #pragma unroll
    for (int m=0;m<4;m++)
      #pragma unroll
      for (int n=0;n<4;n++)
        acc[m][n] = __builtin_amdgcn_mfma_f32_16x16x32_bf16(af[m], bf[n], acc[m][n], 0, 0, 0);
  }

  const int crow0 = m0 + wr*64;
  const int ccol0 = n0 + wc*64;
  #pragma unroll
  for (int n=0;n<4;n++){
    const int col = ccol0 + n*16 + l15;
    const float bv = bias[col];
    #pragma unroll
    for (int m=0;m<4;m++){
      #pragma unroll
      for (int r=0;r<4;r++){
        const int row = crow0 + m*16 + g*4 + r;
        const float v = acc[m][n][r] + bv;
        if (OUT_F32) ((float*)Cout)[(size_t)row * N + col] = v;
        else         ((unsigned short*)Cout)[(size_t)row * N + col] = f2bf(v);
      }
    }
  }
}

// ---------------- causal flash attention, swapped-operand 32x32 MFMA ----------------
// 256 threads = 4 waves; wave w owns q rows [qb*128+w*32, +32). KV tile = 128,
// double-buffered with prefetch (stage t+1 before compute t, one barrier per tile).
// S^T = mfma(K, Q^T): col=q(lane&31), row=kv((r&3)+8*(r>>2)+4*hi); exp2-domain softmax.
// O^T = mfma(V^T(tr-read), P^T(cvt_pk + shfl_xor)): col=q -> per-lane rescale.
__global__ __launch_bounds__(256) void attn_k(const unsigned short* __restrict__ qkv,
                                              unsigned short* __restrict__ aout)
{
  const int qb = (int)gridDim.x - 1 - (int)blockIdx.x;   // heavy tiles first
  const int h = blockIdx.y, b = blockIdx.z;
  const int tid = threadIdx.x;
  const int w = tid >> 6, lane = tid & 63;
  const int l31 = lane & 31, hi = lane >> 5;

  __shared__ unsigned short Ks[2][128*64];   // [kv][d] XOR-swizzled rows (byte ^= (row&7)<<4)
  __shared__ unsigned short Vs[2][128*64];   // subtiled for ds_read_b64_tr_b16

  const size_t rs = 3 * NXDIM;
  const unsigned short* Qg = qkv + (size_t)b * SS * rs + h * HDIM;
  const unsigned short* Kg = Qg + NXDIM;
  const unsigned short* Vg = Qg + 2 * NXDIM;

  const int q0w = qb*128 + w*32;
  const int q   = q0w + l31;
  const int qw_hi = q0w + 31;

  short8 qf[4];
  #pragma unroll
  for (int c=0;c<4;c++)
    qf[c] = *(const short8*)(Qg + (size_t)q * rs + c*16 + 8*hi);

  f32x16 O0, O1;
  #pragma unroll
  for (int r=0;r<16;r++){ O0[r]=0.f; O1[r]=0.f; }
  float m_run = -1e30f, l_run = 0.f;
  const float SC2 = 0.125f * 1.44269504089f;   // scale * log2(e)

  // staging source coords (verified maps; 16 chunks of 8 kv rows per tile)
  const int krow_in = lane >> 3;
  const int kcol    = 8 * ((lane & 7) ^ (lane >> 3));
  const int v_d     = ((lane >> 3) & 3) * 16 + 8 * (lane & 1);
  const unsigned vtr_base = (unsigned)(size_t)&Vs[0][0] + 8u*(unsigned)lane + 768u*(unsigned)hi;

  // stage tile tt (128 kv rows) into buffer bi: 16 chunks, 4 per wave
  auto stage = [&](int bi, int tt){
    #pragma unroll
    for (int j=0;j<4;j++){
      const int ch = w*4 + j;
      const int krow = tt*128 + ch*8 + krow_in;
      gload_lds16(Kg + (size_t)krow * rs + kcol, &Ks[bi][ch*512]);
      const int vkv = tt*128 + (ch*2 + hi)*4 + ((lane>>1)&3);
      gload_lds16(Vg + (size_t)vkv * rs + v_d, &Vs[bi][ch*512]);
    }
  };

  stage(0, 0);
  __syncthreads();
  int cur = 0;

  for (int t = 0; t <= qb; ++t){
    if (t < qb) stage(cur^1, t+1);          // prefetch next tile (hides under compute)

    const char* Kb = (const char*)&Ks[cur][0];
    const unsigned vb = vtr_base + (unsigned)(cur * 16384);

    #pragma unroll
    for (int kvs=0;kvs<4;kvs++){
      const int kv_lo = t*128 + kvs*32;
      if (kv_lo > qw_hi) continue;          // wave-uniform skip (fully masked)

      // ---- S^T = K * Q^T ----
      f32x16 S;
      #pragma unroll
      for (int r=0;r<16;r++) S[r] = 0.f;
      __builtin_amdgcn_s_setprio(1);
      #pragma unroll
      for (int c=0;c<4;c++){
        const int row = kvs*32 + l31;
        short8 kf = *(const short8*)(Kb + row*128 + ((c*32 + 16*hi) ^ ((row&7)<<4)));
        S = __builtin_amdgcn_mfma_f32_32x32x16_bf16(kf, qf[c], S, 0, 0, 0);
      }
      __builtin_amdgcn_s_setprio(0);

      // ---- online softmax, exp2 domain (per-lane column q) ----
      float mx = -1e30f;
      if (kv_lo + 31 > q0w){
        #pragma unroll
        for (int r=0;r<16;r++){
          const int kv = kv_lo + (r&3) + 8*(r>>2) + 4*hi;
          float sv = (kv <= q) ? S[r]*SC2 : -1e30f;
          S[r] = sv; mx = fmaxf(mx, sv);
        }
      } else {
        #pragma unroll
        for (int r=0;r<16;r++){ float sv = S[r]*SC2; S[r] = sv; mx = fmaxf(mx, sv); }
      }
      mx = fmaxf(mx, __shfl_xor(mx, 32));
      const float m_new = fmaxf(m_run, mx);
      const float corr = __builtin_exp2f(m_run - m_new);
      m_run = m_new;
      float ls = 0.f;
      #pragma unroll
      for (int r=0;r<16;r++){ const float pe = __builtin_exp2f(S[r] - m_new); S[r] = pe; ls += pe; }
      ls += __shfl_xor(ls, 32);
      l_run = l_run * corr + ls;
      #pragma unroll
      for (int r=0;r<16;r++){ O0[r] *= corr; O1[r] *= corr; }

      // ---- P^T -> bf16 fragment via cvt_pk + shfl_xor half-exchange ----
      unsigned pk[8], xk[8];
      #pragma unroll
      for (int i=0;i<8;i++) pk[i] = cvt_pk_bf16(S[2*i], S[2*i+1]);
      #pragma unroll
      for (int i=0;i<8;i++) xk[i] = (unsigned)__shfl_xor((int)pk[i], 32);
      short8 pfrag[2];
      #pragma unroll
      for (int c=0;c<2;c++){
        union { unsigned u[4]; short8 s; } pw;
        pw.u[0] = hi ? xk[4*c+2] : pk[4*c+0];
        pw.u[1] = hi ? xk[4*c+3] : pk[4*c+1];
        pw.u[2] = hi ? pk[4*c+2] : xk[4*c+0];
        pw.u[3] = hi ? pk[4*c+3] : xk[4*c+1];
        pfrag[c] = pw.s;
      }

      // ---- V^T fragments via ds_read_b64_tr_b16, then O^T += V^T * P^T ----
      int2v tv[8];
      #pragma unroll
      for (int c=0;c<2;c++)
        #pragma unroll
        for (int dh=0;dh<2;dh++)
          #pragma unroll
          for (int eb=0;eb<2;eb++)
            tv[c*4+dh*2+eb] = ds_tr_b16(vb + (unsigned)((kvs*8 + c*4 + eb)*512 + dh*256));
      asm volatile("s_waitcnt lgkmcnt(0)" ::: "memory");
      __builtin_amdgcn_sched_barrier(0);

      __builtin_amdgcn_s_setprio(1);
      #pragma unroll
      for (int c=0;c<2;c++){
        union { int2v t[2]; short8 s; } v0, v1;
        v0.t[0] = tv[c*4+0]; v0.t[1] = tv[c*4+1];
        v1.t[0] = tv[c*4+2]; v1.t[1] = tv[c*4+3];
        O0 = __builtin_amdgcn_mfma_f32_32x32x16_bf16(v0.s, pfrag[c], O0, 0, 0, 0);
        O1 = __builtin_amdgcn_mfma_f32_32x32x16_bf16(v1.s, pfrag[c], O1, 0, 0, 0);
      }
      __builtin_amdgcn_s_setprio(0);
    }

    __syncthreads();   // drains prefetch (vmcnt) + protects buffer reuse
    cur ^= 1;
  }

  // ---- epilogue: O^T /= l, write aout[b][q][h*64 + d] ----
  const float inv = 1.f / l_run;
  unsigned short* dst = aout + ((size_t)b*SS + q) * NXDIM + h*HDIM;
  #pragma unroll
  for (int g4=0; g4<4; g4++){
    ushort4v a0, a1;
    #pragma unroll
    for (int i=0;i<4;i++){ a0[i] = f2bf(O0[4*g4+i]*inv); a1[i] = f2bf(O1[4*g4+i]*inv); }
    *(ushort4v*)(dst + 8*g4 + 4*hi)      = a0;
    *(ushort4v*)(dst + 32 + 8*g4 + 4*hi) = a1;
  }
}

extern "C" void kernel_launch(void* const* d_in, const int* in_sizes, int n_in,
                              void* d_out, int out_size, void* d_ws, size_t ws_size,
                              hipStream_t stream){
  (void)in_sizes; (void)n_in; (void)out_size; (void)ws_size;
  const float* x      = (const float*)d_in[0];   // [2,2048,1024]
  const float* w_attn = (const float*)d_in[1];   // [1024,3072]
  const float* b_attn = (const float*)d_in[2];   // [3072]
  const float* w_proj = (const float*)d_in[3];   // [1024,1024]
  const float* b_proj = (const float*)d_in[4];   // [1024]
  float* out = (float*)d_out;                    // [2,2048,1024] f32

  unsigned short* xb   = (unsigned short*)d_ws;              // 4096x1024 bf16
  unsigned short* waT  = xb  + (size_t)4096*1024;            // 3072x1024 bf16 (W_attn^T)
  unsigned short* wpT  = waT + (size_t)3072*1024;            // 1024x1024 bf16 (W_proj^T)
  unsigned short* qkv  = wpT + (size_t)1024*1024;            // 4096x3072 bf16
  unsigned short* aout = qkv + (size_t)4096*3072;            // 4096x1024 bf16

  f32_to_bf16_k<<<4096, 256, 0, stream>>>(x, xb, 4096*1024/4);
  transpose_bf16_k<<<dim3(3072/32, 1024/32), dim3(32,8), 0, stream>>>(w_attn, waT, 1024, 3072);
  transpose_bf16_k<<<dim3(1024/32, 1024/32), dim3(32,8), 0, stream>>>(w_proj, wpT, 1024, 1024);

  gemm_bt_k<false><<<dim3(3072/128, 4096/128), 256, 0, stream>>>(xb, waT, b_attn, (void*)qkv, 4096, 3072, 1024);
  attn_k<<<dim3(SS/128, NHEADS, BB), 256, 0, stream>>>(qkv, aout);
  gemm_bt_k<true><<<dim3(1024/128, 4096/128), 256, 0, stream>>>(aout, wpT, b_proj, (void*)out, 4096, 1024, 1024);
}

// Round 7
// 166.083 us; speedup vs baseline: 1.1609x; 1.0966x over previous
//
#include <hip/hip_runtime.h>
#include <stdint.h>

typedef __attribute__((ext_vector_type(8))) short short8;
typedef __attribute__((ext_vector_type(4))) float f32x4;
typedef __attribute__((ext_vector_type(16))) float f32x16;
typedef __attribute__((ext_vector_type(4))) unsigned short ushort4v;
typedef __attribute__((ext_vector_type(2))) int int2v;

#define BB 2
#define SS 2048
#define NXDIM 1024
#define NHEADS 16
#define HDIM 64

__device__ __forceinline__ unsigned short f2bf(float f){
  unsigned int u = __float_as_uint(f);
  u += 0x7fffu + ((u >> 16) & 1u);
  return (unsigned short)(u >> 16);
}

__device__ __forceinline__ void gload_lds16(const void* g, void* l){
  __builtin_amdgcn_global_load_lds((const __attribute__((address_space(1))) void*)g,
                                   (__attribute__((address_space(3))) void*)l, 16, 0, 0);
}

__device__ __forceinline__ unsigned cvt_pk_bf16(float lo, float hi){
  unsigned r;
  asm("v_cvt_pk_bf16_f32 %0, %1, %2" : "=v"(r) : "v"(lo), "v"(hi));
  return r;
}

__device__ __forceinline__ int2v ds_tr_b16(unsigned addr){
  int2v r;
  asm volatile("ds_read_b64_tr_b16 %0, %1" : "=v"(r) : "v"(addr));
  return r;
}

// ---------------- f32 -> bf16 convert (vectorized) ----------------
__global__ __launch_bounds__(256) void f32_to_bf16_k(const float* __restrict__ in,
                                                     unsigned short* __restrict__ out, int n4){
  int i = blockIdx.x * 256 + threadIdx.x;
  if (i >= n4) return;
  float4 v = ((const float4*)in)[i];
  ushort4v r = { f2bf(v.x), f2bf(v.y), f2bf(v.z), f2bf(v.w) };
  ((ushort4v*)out)[i] = r;
}

// ---------------- f32 [R][C] -> bf16 transposed [C][R] ----------------
__global__ __launch_bounds__(256) void transpose_bf16_k(const float* __restrict__ in,
                                                        unsigned short* __restrict__ out,
                                                        int R, int C){
  __shared__ float t[32][33];
  const int bx = blockIdx.x * 32, by = blockIdx.y * 32;
  const int tx = threadIdx.x, ty = threadIdx.y;
  #pragma unroll
  for (int i = ty; i < 32; i += 8)
    t[i][tx] = in[(size_t)(by + i) * C + bx + tx];
  __syncthreads();
  #pragma unroll
  for (int i = ty; i < 32; i += 8)
    out[(size_t)(bx + i) * R + by + tx] = f2bf(t[tx][i]);
}

// ---------------- bf16 GEMM: C[M,N] = A[M,K] * BT[N,K]^T + bias ----------------
template<bool OUT_F32>
__global__ __launch_bounds__(256) void gemm_bt_k(const unsigned short* __restrict__ A,
                                                 const unsigned short* __restrict__ BT,
                                                 const float* __restrict__ bias,
                                                 void* __restrict__ Cout,
                                                 int M, int N, int K)
{
  __shared__ unsigned short As[128*32];
  __shared__ unsigned short Bs[128*32];
  const int tid = threadIdx.x;
  const int w = tid >> 6, lane = tid & 63;
  const int l15 = lane & 15, g = lane >> 4;
  const int wr = w >> 1, wc = w & 1;
  const int m0 = blockIdx.y * 128, n0 = blockIdx.x * 128;

  f32x4 acc[4][4];
  #pragma unroll
  for (int m=0;m<4;m++)
    #pragma unroll
    for (int n=0;n<4;n++) acc[m][n] = (f32x4){0.f,0.f,0.f,0.f};

  const int scol = (lane & 3) * 8;

  for (int k0 = 0; k0 < K; k0 += 32){
    __syncthreads();
    #pragma unroll
    for (int j=0;j<2;j++){
      const int row = w*32 + j*16 + (lane >> 2);
      const unsigned short* ga = A  + (size_t)(m0 + row) * K + (k0 + scol);
      const unsigned short* gb = BT + (size_t)(n0 + row) * K + (k0 + scol);
      gload_lds16(ga, &As[(w*32 + j*16) * 32]);
      gload_lds16(gb, &Bs[(w*32 + j*16) * 32]);
    }
    __syncthreads();

    short8 af[4], bf[4];
    #pragma unroll
    for (int m=0;m<4;m++) af[m] = *(const short8*)&As[(wr*64 + m*16 + l15)*32 + g*8];
    #pragma unroll
    for (int n=0;n<4;n++) bf[n] = *(const short8*)&Bs[(wc*64 + n*16 + l15)*32 + g*8];
    #pragma unroll
    for (int m=0;m<4;m++)
      #pragma unroll
      for (int n=0;n<4;n++)
        acc[m][n] = __builtin_amdgcn_mfma_f32_16x16x32_bf16(af[m], bf[n], acc[m][n], 0, 0, 0);
  }

  const int crow0 = m0 + wr*64;
  const int ccol0 = n0 + wc*64;
  #pragma unroll
  for (int n=0;n<4;n++){
    const int col = ccol0 + n*16 + l15;
    const float bv = bias[col];
    #pragma unroll
    for (int m=0;m<4;m++){
      #pragma unroll
      for (int r=0;r<4;r++){
        const int row = crow0 + m*16 + g*4 + r;
        const float v = acc[m][n][r] + bv;
        if (OUT_F32) ((float*)Cout)[(size_t)row * N + col] = v;
        else         ((unsigned short*)Cout)[(size_t)row * N + col] = f2bf(v);
      }
    }
  }
}

// ---------------- causal flash attention, swapped-operand 32x32 MFMA ----------------
// 512 threads = 8 waves = 4 q-waves x 2 kv-parities. QBLK=128: q-wave qw owns rows
// [qb*128+qw*32,+32). Parity p processes 64-kv tiles t with t&1==p, own dbuf pair,
// prefetch (one barrier/tile). End: parity-merge (m,l,O) in LDS, p=0 writes out.
// S^T = mfma(K, Q^T): col=q(lane&31), row=kv((r&3)+8*(r>>2)+4*hi); exp2 softmax,
// defer-rescale THR=8. O^T = mfma(V^T(tr-read), P^T(cvt_pk+shfl)).
__global__ __launch_bounds__(512) void attn_k(const unsigned short* __restrict__ qkv,
                                              unsigned short* __restrict__ aout)
{
  const int qb = (int)gridDim.x - 1 - (int)blockIdx.x;   // heavy tiles first
  const int h = blockIdx.y, b = blockIdx.z;
  const int tid = threadIdx.x;
  const int w = tid >> 6, lane = tid & 63;
  const int l31 = lane & 31, hi = lane >> 5;
  const int qw = w >> 1, p = w & 1;

  __shared__ unsigned short lds[32768];              // 64 KB
  unsigned short* Ksb = lds;                         // [par][buf][64*64] K, XOR-swizzled rows
  unsigned short* Vsb = lds + 16384;                 // [par][buf][64*64] V, tr_b16 subtiled

  const size_t rs = 3 * NXDIM;
  const unsigned short* Qg = qkv + (size_t)b * SS * rs + h * HDIM;
  const unsigned short* Kg = Qg + NXDIM;
  const unsigned short* Vg = Qg + 2 * NXDIM;

  const int q0w = qb*128 + qw*32;
  const int q   = q0w + l31;
  const int qw_hi = q0w + 31;

  short8 qf[4];
  #pragma unroll
  for (int c=0;c<4;c++)
    qf[c] = *(const short8*)(Qg + (size_t)q * rs + c*16 + 8*hi);

  f32x16 O0, O1;
  #pragma unroll
  for (int r=0;r<16;r++){ O0[r]=0.f; O1[r]=0.f; }
  float m_run = -1e30f, l_run = 0.f;
  const float SC2 = 0.125f * 1.44269504089f;   // scale * log2(e)

  // staging source coords (R4-verified maps, KVBLK=64: 8 chunks x 8 kv rows)
  const int krow_in = lane >> 3;
  const int kcol    = 8 * ((lane & 7) ^ (lane >> 3));
  const int v_d     = ((lane >> 3) & 3) * 16 + 8 * (lane & 1);
  const unsigned vtr_base = (unsigned)(size_t)Vsb + 8u*(unsigned)lane + 768u*(unsigned)hi;

  // stage own-parity tile tt into parity-p buffer bi: 4 q-waves cover 8 chunks
  auto stage = [&](int bi, int tt){
    unsigned short* Kd = Ksb + (p*2 + bi)*4096;
    unsigned short* Vd = Vsb + (p*2 + bi)*4096;
    #pragma unroll
    for (int j=0;j<2;j++){
      const int ch = qw*2 + j;
      const int krow = tt*64 + ch*8 + krow_in;
      gload_lds16(Kg + (size_t)krow * rs + kcol, Kd + ch*512);
      const int vkv = tt*64 + (ch*2 + hi)*4 + ((lane>>1)&3);
      gload_lds16(Vg + (size_t)vkv * rs + v_d, Vd + ch*512);
    }
  };

  const int tmax = 2*qb + 1;
  stage(0, p);
  __syncthreads();
  int cur = 0;

  for (int t = p; t <= tmax; t += 2){
    if (t + 2 <= tmax) stage(cur^1, t+2);   // prefetch own next tile

    const char* Kb = (const char*)(Ksb + (p*2 + cur)*4096);
    const unsigned vb = vtr_base + (unsigned)((p*2 + cur)*8192);

    #pragma unroll
    for (int kvs=0;kvs<2;kvs++){
      const int kv_lo = t*64 + kvs*32;
      if (kv_lo > qw_hi) continue;          // wave-uniform skip (fully masked)

      // ---- S^T = K * Q^T ----
      f32x16 S;
      #pragma unroll
      for (int r=0;r<16;r++) S[r] = 0.f;
      __builtin_amdgcn_s_setprio(1);
      #pragma unroll
      for (int c=0;c<4;c++){
        const int row = kvs*32 + l31;
        short8 kf = *(const short8*)(Kb + row*128 + ((c*32 + 16*hi) ^ ((row&7)<<4)));
        S = __builtin_amdgcn_mfma_f32_32x32x16_bf16(kf, qf[c], S, 0, 0, 0);
      }
      __builtin_amdgcn_s_setprio(0);

      // ---- online softmax, exp2 domain, 4-way ILP trees, defer-rescale ----
      float mA=-1e30f, mB=-1e30f, mC=-1e30f, mD=-1e30f;
      if (kv_lo + 31 > q0w){
        #pragma unroll
        for (int r=0;r<16;r+=4){
          const int kvb = kv_lo + 8*(r>>2) + 4*hi;
          float s0 = (kvb+0 <= q) ? S[r+0]*SC2 : -1e30f;
          float s1 = (kvb+1 <= q) ? S[r+1]*SC2 : -1e30f;
          float s2 = (kvb+2 <= q) ? S[r+2]*SC2 : -1e30f;
          float s3 = (kvb+3 <= q) ? S[r+3]*SC2 : -1e30f;
          S[r+0]=s0; S[r+1]=s1; S[r+2]=s2; S[r+3]=s3;
          mA = fmaxf(mA, s0); mB = fmaxf(mB, s1); mC = fmaxf(mC, s2); mD = fmaxf(mD, s3);
        }
      } else {
        #pragma unroll
        for (int r=0;r<16;r+=4){
          float s0=S[r+0]*SC2, s1=S[r+1]*SC2, s2=S[r+2]*SC2, s3=S[r+3]*SC2;
          S[r+0]=s0; S[r+1]=s1; S[r+2]=s2; S[r+3]=s3;
          mA = fmaxf(mA, s0); mB = fmaxf(mB, s1); mC = fmaxf(mC, s2); mD = fmaxf(mD, s3);
        }
      }
      float mx = fmaxf(fmaxf(mA,mB), fmaxf(mC,mD));
      mx = fmaxf(mx, __shfl_xor(mx, 32));

      if (!__all(mx <= m_run + 8.f)){       // rescale only when max grows past THR
        const float m_new = fmaxf(m_run, mx);
        const float corr = __builtin_exp2f(m_run - m_new);
        m_run = m_new;
        l_run *= corr;
        #pragma unroll
        for (int r=0;r<16;r++){ O0[r] *= corr; O1[r] *= corr; }
      }

      float lA=0.f, lB=0.f, lC=0.f, lD=0.f;
      #pragma unroll
      for (int r=0;r<16;r+=4){
        float p0=__builtin_exp2f(S[r+0]-m_run), p1=__builtin_exp2f(S[r+1]-m_run);
        float p2=__builtin_exp2f(S[r+2]-m_run), p3=__builtin_exp2f(S[r+3]-m_run);
        S[r+0]=p0; S[r+1]=p1; S[r+2]=p2; S[r+3]=p3;
        lA+=p0; lB+=p1; lC+=p2; lD+=p3;
      }
      float ls = (lA+lB) + (lC+lD);
      ls += __shfl_xor(ls, 32);
      l_run += ls;

      // ---- P^T -> bf16 fragment via cvt_pk + shfl_xor half-exchange ----
      unsigned pk[8], xk[8];
      #pragma unroll
      for (int i=0;i<8;i++) pk[i] = cvt_pk_bf16(S[2*i], S[2*i+1]);
      #pragma unroll
      for (int i=0;i<8;i++) xk[i] = (unsigned)__shfl_xor((int)pk[i], 32);
      short8 pfrag[2];
      #pragma unroll
      for (int c=0;c<2;c++){
        union { unsigned u[4]; short8 s; } pw;
        pw.u[0] = hi ? xk[4*c+2] : pk[4*c+0];
        pw.u[1] = hi ? xk[4*c+3] : pk[4*c+1];
        pw.u[2] = hi ? pk[4*c+2] : xk[4*c+0];
        pw.u[3] = hi ? pk[4*c+3] : xk[4*c+1];
        pfrag[c] = pw.s;
      }

      // ---- V^T fragments via ds_read_b64_tr_b16, then O^T += V^T * P^T ----
      int2v tv[8];
      #pragma unroll
      for (int c=0;c<2;c++)
        #pragma unroll
        for (int dh=0;dh<2;dh++)
          #pragma unroll
          for (int eb=0;eb<2;eb++)
            tv[c*4+dh*2+eb] = ds_tr_b16(vb + (unsigned)((kvs*8 + c*4 + eb)*512 + dh*256));
      asm volatile("s_waitcnt lgkmcnt(0)" ::: "memory");
      __builtin_amdgcn_sched_barrier(0);

      __builtin_amdgcn_s_setprio(1);
      #pragma unroll
      for (int c=0;c<2;c++){
        union { int2v t[2]; short8 s; } v0, v1;
        v0.t[0] = tv[c*4+0]; v0.t[1] = tv[c*4+1];
        v1.t[0] = tv[c*4+2]; v1.t[1] = tv[c*4+3];
        O0 = __builtin_amdgcn_mfma_f32_32x32x16_bf16(v0.s, pfrag[c], O0, 0, 0, 0);
        O1 = __builtin_amdgcn_mfma_f32_32x32x16_bf16(v1.s, pfrag[c], O1, 0, 0, 0);
      }
      __builtin_amdgcn_s_setprio(0);
    }

    __syncthreads();   // drains prefetch (vmcnt) + protects buffer reuse
    cur ^= 1;
  }

  // ---- merge parity partials (p=1 -> LDS, p=0 merges + writes) ----
  float* sm = (float*)lds + qw * (64*34);
  if (p){
    #pragma unroll
    for (int r=0;r<16;r++){ sm[lane*34 + r] = O0[r]; sm[lane*34 + 16 + r] = O1[r]; }
    sm[lane*34 + 32] = m_run;
    sm[lane*34 + 33] = l_run;
  }
  __syncthreads();
  if (!p){
    const float m1 = sm[lane*34 + 32], l1 = sm[lane*34 + 33];
    const float mm = fmaxf(m_run, m1);
    const float c0 = __builtin_exp2f(m_run - mm);
    const float c1 = __builtin_exp2f(m1 - mm);
    const float inv = 1.f / (l_run*c0 + l1*c1);
    unsigned short* dst = aout + ((size_t)b*SS + q) * NXDIM + h*HDIM;
    #pragma unroll
    for (int g4=0; g4<4; g4++){
      ushort4v a0, a1;
      #pragma unroll
      for (int i=0;i<4;i++){
        a0[i] = f2bf((O0[4*g4+i]*c0 + sm[lane*34 + 4*g4+i]*c1) * inv);
        a1[i] = f2bf((O1[4*g4+i]*c0 + sm[lane*34 + 16 + 4*g4+i]*c1) * inv);
      }
      *(ushort4v*)(dst + 8*g4 + 4*hi)      = a0;
      *(ushort4v*)(dst + 32 + 8*g4 + 4*hi) = a1;
    }
  }
}

extern "C" void kernel_launch(void* const* d_in, const int* in_sizes, int n_in,
                              void* d_out, int out_size, void* d_ws, size_t ws_size,
                              hipStream_t stream){
  (void)in_sizes; (void)n_in; (void)out_size; (void)ws_size;
  const float* x      = (const float*)d_in[0];   // [2,2048,1024]
  const float* w_attn = (const float*)d_in[1];   // [1024,3072]
  const float* b_attn = (const float*)d_in[2];   // [3072]
  const float* w_proj = (const float*)d_in[3];   // [1024,1024]
  const float* b_proj = (const float*)d_in[4];   // [1024]
  float* out = (float*)d_out;                    // [2,2048,1024] f32

  unsigned short* xb   = (unsigned short*)d_ws;              // 4096x1024 bf16
  unsigned short* waT  = xb  + (size_t)4096*1024;            // 3072x1024 bf16 (W_attn^T)
  unsigned short* wpT  = waT + (size_t)3072*1024;            // 1024x1024 bf16 (W_proj^T)
  unsigned short* qkv  = wpT + (size_t)1024*1024;            // 4096x3072 bf16
  unsigned short* aout = qkv + (size_t)4096*3072;            // 4096x1024 bf16

  f32_to_bf16_k<<<4096, 256, 0, stream>>>(x, xb, 4096*1024/4);
  transpose_bf16_k<<<dim3(3072/32, 1024/32), dim3(32,8), 0, stream>>>(w_attn, waT, 1024, 3072);
  transpose_bf16_k<<<dim3(1024/32, 1024/32), dim3(32,8), 0, stream>>>(w_proj, wpT, 1024, 1024);

  gemm_bt_k<false><<<dim3(3072/128, 4096/128), 256, 0, stream>>>(xb, waT, b_attn, (void*)qkv, 4096, 3072, 1024);
  attn_k<<<dim3(SS/128, NHEADS, BB), 512, 0, stream>>>(qkv, aout);
  gemm_bt_k<true><<<dim3(1024/128, 4096/128), 256, 0, stream>>>(aout, wpT, b_proj, (void*)out, 4096, 1024, 1024);
}

// Round 8
// 158.422 us; speedup vs baseline: 1.2171x; 1.0484x over previous
//
#include <hip/hip_runtime.h>
#include <stdint.h>

typedef __attribute__((ext_vector_type(8))) short short8;
typedef __attribute__((ext_vector_type(4))) float f32x4;
typedef __attribute__((ext_vector_type(16))) float f32x16;
typedef __attribute__((ext_vector_type(4))) unsigned short ushort4v;
typedef __attribute__((ext_vector_type(2))) int int2v;

#define BB 2
#define SS 2048
#define NXDIM 1024
#define NHEADS 16
#define HDIM 64

__device__ __forceinline__ unsigned short f2bf(float f){
  unsigned int u = __float_as_uint(f);
  u += 0x7fffu + ((u >> 16) & 1u);
  return (unsigned short)(u >> 16);
}

__device__ __forceinline__ void gload_lds16(const void* g, void* l){
  __builtin_amdgcn_global_load_lds((const __attribute__((address_space(1))) void*)g,
                                   (__attribute__((address_space(3))) void*)l, 16, 0, 0);
}

__device__ __forceinline__ unsigned cvt_pk_bf16(float lo, float hi){
  unsigned r;
  asm("v_cvt_pk_bf16_f32 %0, %1, %2" : "=v"(r) : "v"(lo), "v"(hi));
  return r;
}

__device__ __forceinline__ int2v ds_tr_b16(unsigned addr){
  int2v r;
  asm volatile("ds_read_b64_tr_b16 %0, %1" : "=v"(r) : "v"(addr));
  return r;
}

// permlane32_swap (SSA builtin, no operand aliasing): returns {dst', src'} where
// dst'[l<32]=a[l], dst'[l>=32]=b[l-32]; src'[l<32]=a[l+32], src'[l>=32]=b[l].
__device__ __forceinline__ int2v plswap(int a, int b){
  return __builtin_amdgcn_permlane32_swap(a, b, false, false);
}
__device__ __forceinline__ float plmax(float x){
  int2v r = plswap(__float_as_int(x), __float_as_int(x));
  return fmaxf(__int_as_float(r.x), __int_as_float(r.y));
}
__device__ __forceinline__ float pladd(float x){
  int2v r = plswap(__float_as_int(x), __float_as_int(x));
  return __int_as_float(r.x) + __int_as_float(r.y);
}

// ---------------- f32 -> bf16 convert (vectorized) ----------------
__global__ __launch_bounds__(256) void f32_to_bf16_k(const float* __restrict__ in,
                                                     unsigned short* __restrict__ out, int n4){
  int i = blockIdx.x * 256 + threadIdx.x;
  if (i >= n4) return;
  float4 v = ((const float4*)in)[i];
  ushort4v r = { f2bf(v.x), f2bf(v.y), f2bf(v.z), f2bf(v.w) };
  ((ushort4v*)out)[i] = r;
}

// ---------------- f32 [R][C] -> bf16 transposed [C][R] ----------------
__global__ __launch_bounds__(256) void transpose_bf16_k(const float* __restrict__ in,
                                                        unsigned short* __restrict__ out,
                                                        int R, int C){
  __shared__ float t[32][33];
  const int bx = blockIdx.x * 32, by = blockIdx.y * 32;
  const int tx = threadIdx.x, ty = threadIdx.y;
  #pragma unroll
  for (int i = ty; i < 32; i += 8)
    t[i][tx] = in[(size_t)(by + i) * C + bx + tx];
  __syncthreads();
  #pragma unroll
  for (int i = ty; i < 32; i += 8)
    out[(size_t)(bx + i) * R + by + tx] = f2bf(t[tx][i]);
}

// ---------------- bf16 GEMM: C[M,N] = A[M,K] * BT[N,K]^T + bias ----------------
template<bool OUT_F32>
__global__ __launch_bounds__(256) void gemm_bt_k(const unsigned short* __restrict__ A,
                                                 const unsigned short* __restrict__ BT,
                                                 const float* __restrict__ bias,
                                                 void* __restrict__ Cout,
                                                 int M, int N, int K)
{
  __shared__ unsigned short As[128*32];
  __shared__ unsigned short Bs[128*32];
  const int tid = threadIdx.x;
  const int w = tid >> 6, lane = tid & 63;
  const int l15 = lane & 15, g = lane >> 4;
  const int wr = w >> 1, wc = w & 1;
  const int m0 = blockIdx.y * 128, n0 = blockIdx.x * 128;

  f32x4 acc[4][4];
  #pragma unroll
  for (int m=0;m<4;m++)
    #pragma unroll
    for (int n=0;n<4;n++) acc[m][n] = (f32x4){0.f,0.f,0.f,0.f};

  const int scol = (lane & 3) * 8;

  for (int k0 = 0; k0 < K; k0 += 32){
    __syncthreads();
    #pragma unroll
    for (int j=0;j<2;j++){
      const int row = w*32 + j*16 + (lane >> 2);
      const unsigned short* ga = A  + (size_t)(m0 + row) * K + (k0 + scol);
      const unsigned short* gb = BT + (size_t)(n0 + row) * K + (k0 + scol);
      gload_lds16(ga, &As[(w*32 + j*16) * 32]);
      gload_lds16(gb, &Bs[(w*32 + j*16) * 32]);
    }
    __syncthreads();

    short8 af[4], bf[4];
    #pragma unroll
    for (int m=0;m<4;m++) af[m] = *(const short8*)&As[(wr*64 + m*16 + l15)*32 + g*8];
    #pragma unroll
    for (int n=0;n<4;n++) bf[n] = *(const short8*)&Bs[(wc*64 + n*16 + l15)*32 + g*8];
    #pragma unroll
    for (int m=0;m<4;m++)
      #pragma unroll
      for (int n=0;n<4;n++)
        acc[m][n] = __builtin_amdgcn_mfma_f32_16x16x32_bf16(af[m], bf[n], acc[m][n], 0, 0, 0);
  }

  const int crow0 = m0 + wr*64;
  const int ccol0 = n0 + wc*64;
  #pragma unroll
  for (int n=0;n<4;n++){
    const int col = ccol0 + n*16 + l15;
    const float bv = bias[col];
    #pragma unroll
    for (int m=0;m<4;m++){
      #pragma unroll
      for (int r=0;r<4;r++){
        const int row = crow0 + m*16 + g*4 + r;
        const float v = acc[m][n][r] + bv;
        if (OUT_F32) ((float*)Cout)[(size_t)row * N + col] = v;
        else         ((unsigned short*)Cout)[(size_t)row * N + col] = f2bf(v);
      }
    }
  }
}

// ---------------- causal flash attention, swapped-operand 32x32 MFMA ----------------
// 512 threads = 8 waves = 4 q-waves x 2 kv-parities (R7-verified structure).
// Softmax lane-exchange via permlane32_swap (VALU) — no ds_bpermute in the loop.
// tr-reads issued BEFORE softmax (latency hides under pure-VALU softmax).
__global__ __launch_bounds__(512) void attn_k(const unsigned short* __restrict__ qkv,
                                              unsigned short* __restrict__ aout)
{
  const int qb = (int)gridDim.x - 1 - (int)blockIdx.x;   // heavy tiles first
  const int h = blockIdx.y, b = blockIdx.z;
  const int tid = threadIdx.x;
  const int w = tid >> 6, lane = tid & 63;
  const int l31 = lane & 31, hi = lane >> 5;
  const int qw = w >> 1, p = w & 1;

  __shared__ unsigned short lds[32768];              // 64 KB
  unsigned short* Ksb = lds;                         // [par][buf][64*64] K, XOR-swizzled rows
  unsigned short* Vsb = lds + 16384;                 // [par][buf][64*64] V, tr_b16 subtiled

  const size_t rs = 3 * NXDIM;
  const unsigned short* Qg = qkv + (size_t)b * SS * rs + h * HDIM;
  const unsigned short* Kg = Qg + NXDIM;
  const unsigned short* Vg = Qg + 2 * NXDIM;

  const int q0w = qb*128 + qw*32;
  const int q   = q0w + l31;
  const int qw_hi = q0w + 31;

  short8 qf[4];
  #pragma unroll
  for (int c=0;c<4;c++)
    qf[c] = *(const short8*)(Qg + (size_t)q * rs + c*16 + 8*hi);

  f32x16 O0, O1;
  #pragma unroll
  for (int r=0;r<16;r++){ O0[r]=0.f; O1[r]=0.f; }
  float m_run = -1e30f, l_run = 0.f;
  const float SC2 = 0.125f * 1.44269504089f;   // scale * log2(e)

  // staging source coords (R4-verified maps, KVBLK=64: 8 chunks x 8 kv rows)
  const int krow_in = lane >> 3;
  const int kcol    = 8 * ((lane & 7) ^ (lane >> 3));
  const int v_d     = ((lane >> 3) & 3) * 16 + 8 * (lane & 1);
  const unsigned vtr_base = (unsigned)(size_t)Vsb + 8u*(unsigned)lane + 768u*(unsigned)hi;

  // stage own-parity tile tt into parity-p buffer bi: 4 q-waves cover 8 chunks
  auto stage = [&](int bi, int tt){
    unsigned short* Kd = Ksb + (p*2 + bi)*4096;
    unsigned short* Vd = Vsb + (p*2 + bi)*4096;
    #pragma unroll
    for (int j=0;j<2;j++){
      const int ch = qw*2 + j;
      const int krow = tt*64 + ch*8 + krow_in;
      gload_lds16(Kg + (size_t)krow * rs + kcol, Kd + ch*512);
      const int vkv = tt*64 + (ch*2 + hi)*4 + ((lane>>1)&3);
      gload_lds16(Vg + (size_t)vkv * rs + v_d, Vd + ch*512);
    }
  };

  const int tmax = 2*qb + 1;
  stage(0, p);
  __syncthreads();
  int cur = 0;

  for (int t = p; t <= tmax; t += 2){
    if (t + 2 <= tmax) stage(cur^1, t+2);   // prefetch own next tile

    const char* Kb = (const char*)(Ksb + (p*2 + cur)*4096);
    const unsigned vb = vtr_base + (unsigned)((p*2 + cur)*8192);

    #pragma unroll
    for (int kvs=0;kvs<2;kvs++){
      const int kv_lo = t*64 + kvs*32;
      if (kv_lo > qw_hi) continue;          // wave-uniform skip (fully masked)

      // ---- S^T = K * Q^T ----
      f32x16 S;
      #pragma unroll
      for (int r=0;r<16;r++) S[r] = 0.f;
      __builtin_amdgcn_s_setprio(1);
      #pragma unroll
      for (int c=0;c<4;c++){
        const int row = kvs*32 + l31;
        short8 kf = *(const short8*)(Kb + row*128 + ((c*32 + 16*hi) ^ ((row&7)<<4)));
        S = __builtin_amdgcn_mfma_f32_32x32x16_bf16(kf, qf[c], S, 0, 0, 0);
      }
      __builtin_amdgcn_s_setprio(0);

      // ---- issue V^T tr-reads EARLY: latency hides under the pure-VALU softmax ----
      int2v tv[8];
      #pragma unroll
      for (int c=0;c<2;c++)
        #pragma unroll
        for (int dh=0;dh<2;dh++)
          #pragma unroll
          for (int eb=0;eb<2;eb++)
            tv[c*4+dh*2+eb] = ds_tr_b16(vb + (unsigned)((kvs*8 + c*4 + eb)*512 + dh*256));

      // ---- online softmax, exp2 domain, 4-way ILP trees, defer-rescale ----
      float mA=-1e30f, mB=-1e30f, mC=-1e30f, mD=-1e30f;
      if (kv_lo + 31 > q0w){
        #pragma unroll
        for (int r=0;r<16;r+=4){
          const int kvb = kv_lo + 8*(r>>2) + 4*hi;
          float s0 = (kvb+0 <= q) ? S[r+0]*SC2 : -1e30f;
          float s1 = (kvb+1 <= q) ? S[r+1]*SC2 : -1e30f;
          float s2 = (kvb+2 <= q) ? S[r+2]*SC2 : -1e30f;
          float s3 = (kvb+3 <= q) ? S[r+3]*SC2 : -1e30f;
          S[r+0]=s0; S[r+1]=s1; S[r+2]=s2; S[r+3]=s3;
          mA = fmaxf(mA, s0); mB = fmaxf(mB, s1); mC = fmaxf(mC, s2); mD = fmaxf(mD, s3);
        }
      } else {
        #pragma unroll
        for (int r=0;r<16;r+=4){
          float s0=S[r+0]*SC2, s1=S[r+1]*SC2, s2=S[r+2]*SC2, s3=S[r+3]*SC2;
          S[r+0]=s0; S[r+1]=s1; S[r+2]=s2; S[r+3]=s3;
          mA = fmaxf(mA, s0); mB = fmaxf(mB, s1); mC = fmaxf(mC, s2); mD = fmaxf(mD, s3);
        }
      }
      float mx = fmaxf(fmaxf(mA,mB), fmaxf(mC,mD));
      mx = plmax(mx);

      if (!__all(mx <= m_run + 8.f)){       // rescale only when max grows past THR
        const float m_new = fmaxf(m_run, mx);
        const float corr = __builtin_exp2f(m_run - m_new);
        m_run = m_new;
        l_run *= corr;
        #pragma unroll
        for (int r=0;r<16;r++){ O0[r] *= corr; O1[r] *= corr; }
      }

      float lA=0.f, lB=0.f, lC=0.f, lD=0.f;
      #pragma unroll
      for (int r=0;r<16;r+=4){
        float p0=__builtin_exp2f(S[r+0]-m_run), p1=__builtin_exp2f(S[r+1]-m_run);
        float p2=__builtin_exp2f(S[r+2]-m_run), p3=__builtin_exp2f(S[r+3]-m_run);
        S[r+0]=p0; S[r+1]=p1; S[r+2]=p2; S[r+3]=p3;
        lA+=p0; lB+=p1; lC+=p2; lD+=p3;
      }
      float ls = (lA+lB) + (lC+lD);
      ls = pladd(ls);
      l_run += ls;

      // ---- P^T -> bf16 fragment: cvt_pk + permlane32_swap half-exchange ----
      unsigned pk[8];
      #pragma unroll
      for (int i=0;i<8;i++) pk[i] = cvt_pk_bf16(S[2*i], S[2*i+1]);
      short8 pfrag[2];
      #pragma unroll
      for (int c=0;c<2;c++){
        int2v r0 = plswap((int)pk[4*c+0], (int)pk[4*c+2]);
        int2v r1 = plswap((int)pk[4*c+1], (int)pk[4*c+3]);
        union { unsigned u[4]; short8 s; } pw;
        pw.u[0] = (unsigned)r0.x; pw.u[1] = (unsigned)r1.x;
        pw.u[2] = (unsigned)r0.y; pw.u[3] = (unsigned)r1.y;
        pfrag[c] = pw.s;
      }

      // ---- wait tr-reads, then O^T += V^T * P^T ----
      asm volatile("s_waitcnt lgkmcnt(0)" ::: "memory");
      __builtin_amdgcn_sched_barrier(0);

      __builtin_amdgcn_s_setprio(1);
      #pragma unroll
      for (int c=0;c<2;c++){
        union { int2v t[2]; short8 s; } v0, v1;
        v0.t[0] = tv[c*4+0]; v0.t[1] = tv[c*4+1];
        v1.t[0] = tv[c*4+2]; v1.t[1] = tv[c*4+3];
        O0 = __builtin_amdgcn_mfma_f32_32x32x16_bf16(v0.s, pfrag[c], O0, 0, 0, 0);
        O1 = __builtin_amdgcn_mfma_f32_32x32x16_bf16(v1.s, pfrag[c], O1, 0, 0, 0);
      }
      __builtin_amdgcn_s_setprio(0);
    }

    __syncthreads();   // drains prefetch (vmcnt) + protects buffer reuse
    cur ^= 1;
  }

  // ---- merge parity partials (p=1 -> LDS, p=0 merges + writes) ----
  float* sm = (float*)lds + qw * (64*34);
  if (p){
    #pragma unroll
    for (int r=0;r<16;r++){ sm[lane*34 + r] = O0[r]; sm[lane*34 + 16 + r] = O1[r]; }
    sm[lane*34 + 32] = m_run;
    sm[lane*34 + 33] = l_run;
  }
  __syncthreads();
  if (!p){
    const float m1 = sm[lane*34 + 32], l1 = sm[lane*34 + 33];
    const float mm = fmaxf(m_run, m1);
    const float c0 = __builtin_exp2f(m_run - mm);
    const float c1 = __builtin_exp2f(m1 - mm);
    const float inv = 1.f / (l_run*c0 + l1*c1);
    unsigned short* dst = aout + ((size_t)b*SS + q) * NXDIM + h*HDIM;
    #pragma unroll
    for (int g4=0; g4<4; g4++){
      ushort4v a0, a1;
      #pragma unroll
      for (int i=0;i<4;i++){
        a0[i] = f2bf((O0[4*g4+i]*c0 + sm[lane*34 + 4*g4+i]*c1) * inv);
        a1[i] = f2bf((O1[4*g4+i]*c0 + sm[lane*34 + 16 + 4*g4+i]*c1) * inv);
      }
      *(ushort4v*)(dst + 8*g4 + 4*hi)      = a0;
      *(ushort4v*)(dst + 32 + 8*g4 + 4*hi) = a1;
    }
  }
}

extern "C" void kernel_launch(void* const* d_in, const int* in_sizes, int n_in,
                              void* d_out, int out_size, void* d_ws, size_t ws_size,
                              hipStream_t stream){
  (void)in_sizes; (void)n_in; (void)out_size; (void)ws_size;
  const float* x      = (const float*)d_in[0];   // [2,2048,1024]
  const float* w_attn = (const float*)d_in[1];   // [1024,3072]
  const float* b_attn = (const float*)d_in[2];   // [3072]
  const float* w_proj = (const float*)d_in[3];   // [1024,1024]
  const float* b_proj = (const float*)d_in[4];   // [1024]
  float* out = (float*)d_out;                    // [2,2048,1024] f32

  unsigned short* xb   = (unsigned short*)d_ws;              // 4096x1024 bf16
  unsigned short* waT  = xb  + (size_t)4096*1024;            // 3072x1024 bf16 (W_attn^T)
  unsigned short* wpT  = waT + (size_t)3072*1024;            // 1024x1024 bf16 (W_proj^T)
  unsigned short* qkv  = wpT + (size_t)1024*1024;            // 4096x3072 bf16
  unsigned short* aout = qkv + (size_t)4096*3072;            // 4096x1024 bf16

  f32_to_bf16_k<<<4096, 256, 0, stream>>>(x, xb, 4096*1024/4);
  transpose_bf16_k<<<dim3(3072/32, 1024/32), dim3(32,8), 0, stream>>>(w_attn, waT, 1024, 3072);
  transpose_bf16_k<<<dim3(1024/32, 1024/32), dim3(32,8), 0, stream>>>(w_proj, wpT, 1024, 1024);

  gemm_bt_k<false><<<dim3(3072/128, 4096/128), 256, 0, stream>>>(xb, waT, b_attn, (void*)qkv, 4096, 3072, 1024);
  attn_k<<<dim3(SS/128, NHEADS, BB), 512, 0, stream>>>(qkv, aout);
  gemm_bt_k<true><<<dim3(1024/128, 4096/128), 256, 0, stream>>>(aout, wpT, b_proj, (void*)out, 4096, 1024, 1024);
}

// Round 10
// 158.003 us; speedup vs baseline: 1.2203x; 1.0027x over previous
//
#include <hip/hip_runtime.h>
#include <stdint.h>

typedef __attribute__((ext_vector_type(8))) short short8;
typedef __attribute__((ext_vector_type(4))) float f32x4;
typedef __attribute__((ext_vector_type(16))) float f32x16;
typedef __attribute__((ext_vector_type(4))) unsigned short ushort4v;
typedef __attribute__((ext_vector_type(2))) int int2v;

#define BB 2
#define SS 2048
#define NXDIM 1024
#define NHEADS 16
#define HDIM 64

__device__ __forceinline__ unsigned short f2bf(float f){
  unsigned int u = __float_as_uint(f);
  u += 0x7fffu + ((u >> 16) & 1u);
  return (unsigned short)(u >> 16);
}

__device__ __forceinline__ void gload_lds16(const void* g, void* l){
  __builtin_amdgcn_global_load_lds((const __attribute__((address_space(1))) void*)g,
                                   (__attribute__((address_space(3))) void*)l, 16, 0, 0);
}

__device__ __forceinline__ unsigned cvt_pk_bf16(float lo, float hi){
  unsigned r;
  asm("v_cvt_pk_bf16_f32 %0, %1, %2" : "=v"(r) : "v"(lo), "v"(hi));
  return r;
}

__device__ __forceinline__ int2v ds_tr_b16(unsigned addr){
  int2v r;
  asm volatile("ds_read_b64_tr_b16 %0, %1" : "=v"(r) : "v"(addr));
  return r;
}

// permlane32_swap (SSA builtin, no operand aliasing)
__device__ __forceinline__ int2v plswap(int a, int b){
  return __builtin_amdgcn_permlane32_swap(a, b, false, false);
}
__device__ __forceinline__ float plmax(float x){
  int2v r = plswap(__float_as_int(x), __float_as_int(x));
  return fmaxf(__int_as_float(r.x), __int_as_float(r.y));
}
__device__ __forceinline__ float pladd(float x){
  int2v r = plswap(__float_as_int(x), __float_as_int(x));
  return __int_as_float(r.x) + __int_as_float(r.y);
}

// ---------------- f32 -> bf16 convert (vectorized) ----------------
__global__ __launch_bounds__(256) void f32_to_bf16_k(const float* __restrict__ in,
                                                     unsigned short* __restrict__ out, int n4){
  int i = blockIdx.x * 256 + threadIdx.x;
  if (i >= n4) return;
  float4 v = ((const float4*)in)[i];
  ushort4v r = { f2bf(v.x), f2bf(v.y), f2bf(v.z), f2bf(v.w) };
  ((ushort4v*)out)[i] = r;
}

// ---------------- f32 [R][C] -> bf16 transposed [C][R] ----------------
__global__ __launch_bounds__(256) void transpose_bf16_k(const float* __restrict__ in,
                                                        unsigned short* __restrict__ out,
                                                        int R, int C){
  __shared__ float t[32][33];
  const int bx = blockIdx.x * 32, by = blockIdx.y * 32;
  const int tx = threadIdx.x, ty = threadIdx.y;
  #pragma unroll
  for (int i = ty; i < 32; i += 8)
    t[i][tx] = in[(size_t)(by + i) * C + bx + tx];
  __syncthreads();
  #pragma unroll
  for (int i = ty; i < 32; i += 8)
    out[(size_t)(bx + i) * R + by + tx] = f2bf(t[tx][i]);
}

// ---------------- bf16 GEMM: C[M,N] = A[M,K] * BT[N,K]^T + bias ----------------
template<bool OUT_F32>
__global__ __launch_bounds__(256) void gemm_bt_k(const unsigned short* __restrict__ A,
                                                 const unsigned short* __restrict__ BT,
                                                 const float* __restrict__ bias,
                                                 void* __restrict__ Cout,
                                                 int M, int N, int K)
{
  __shared__ unsigned short As[128*32];
  __shared__ unsigned short Bs[128*32];
  const int tid = threadIdx.x;
  const int w = tid >> 6, lane = tid & 63;
  const int l15 = lane & 15, g = lane >> 4;
  const int wr = w >> 1, wc = w & 1;
  const int m0 = blockIdx.y * 128, n0 = blockIdx.x * 128;

  f32x4 acc[4][4];
  #pragma unroll
  for (int m=0;m<4;m++)
    #pragma unroll
    for (int n=0;n<4;n++) acc[m][n] = (f32x4){0.f,0.f,0.f,0.f};

  const int scol = (lane & 3) * 8;

  for (int k0 = 0; k0 < K; k0 += 32){
    __syncthreads();
    #pragma unroll
    for (int j=0;j<2;j++){
      const int row = w*32 + j*16 + (lane >> 2);
      const unsigned short* ga = A  + (size_t)(m0 + row) * K + (k0 + scol);
      const unsigned short* gb = BT + (size_t)(n0 + row) * K + (k0 + scol);
      gload_lds16(ga, &As[(w*32 + j*16) * 32]);
      gload_lds16(gb, &Bs[(w*32 + j*16) * 32]);
    }
    __syncthreads();

    short8 af[4], bf[4];
    #pragma unroll
    for (int m=0;m<4;m++) af[m] = *(const short8*)&As[(wr*64 + m*16 + l15)*32 + g*8];
    #pragma unroll
    for (int n=0;n<4;n++) bf[n] = *(const short8*)&Bs[(wc*64 + n*16 + l15)*32 + g*8];
    #pragma unroll
    for (int m=0;m<4;m++)
      #pragma unroll
      for (int n=0;n<4;n++)
        acc[m][n] = __builtin_amdgcn_mfma_f32_16x16x32_bf16(af[m], bf[n], acc[m][n], 0, 0, 0);
  }

  const int crow0 = m0 + wr*64;
  const int ccol0 = n0 + wc*64;
  #pragma unroll
  for (int n=0;n<4;n++){
    const int col = ccol0 + n*16 + l15;
    const float bv = bias[col];
    #pragma unroll
    for (int m=0;m<4;m++){
      #pragma unroll
      for (int r=0;r<4;r++){
        const int row = crow0 + m*16 + g*4 + r;
        const float v = acc[m][n][r] + bv;
        if (OUT_F32) ((float*)Cout)[(size_t)row * N + col] = v;
        else         ((unsigned short*)Cout)[(size_t)row * N + col] = f2bf(v);
      }
    }
  }
}

// ---------------- causal flash attention, swapped-operand 32x32 MFMA ----------------
// 512 threads = 8 waves = 4 q-waves x 2 kv-parities (R7/R8-verified structure).
// Merged 64-kv step: one softmax pass per 64 kv; tr-reads in two batches of 8
// (spill-proof live set) with counted lgkmcnt(8) gating PV0, lgkmcnt(0) gating PV1.
__global__ __launch_bounds__(512) void attn_k(const unsigned short* __restrict__ qkv,
                                              unsigned short* __restrict__ aout)
{
  const int qb = (int)gridDim.x - 1 - (int)blockIdx.x;   // heavy tiles first
  const int h = blockIdx.y, b = blockIdx.z;
  const int tid = threadIdx.x;
  const int w = tid >> 6, lane = tid & 63;
  const int l31 = lane & 31, hi = lane >> 5;
  const int qw = w >> 1, p = w & 1;

  __shared__ unsigned short lds[32768];              // 64 KB
  unsigned short* Ksb = lds;                         // [par][buf][64*64] K, XOR-swizzled rows
  unsigned short* Vsb = lds + 16384;                 // [par][buf][64*64] V, tr_b16 subtiled

  const size_t rs = 3 * NXDIM;
  const unsigned short* Qg = qkv + (size_t)b * SS * rs + h * HDIM;
  const unsigned short* Kg = Qg + NXDIM;
  const unsigned short* Vg = Qg + 2 * NXDIM;

  const int q0w = qb*128 + qw*32;
  const int q   = q0w + l31;
  const int qw_hi = q0w + 31;

  short8 qf[4];
  #pragma unroll
  for (int c=0;c<4;c++)
    qf[c] = *(const short8*)(Qg + (size_t)q * rs + c*16 + 8*hi);

  f32x16 O0, O1;
  #pragma unroll
  for (int r=0;r<16;r++){ O0[r]=0.f; O1[r]=0.f; }
  float m_run = -1e30f, l_run = 0.f;
  const float SC2 = 0.125f * 1.44269504089f;   // scale * log2(e)

  // staging source coords (R4-verified maps, KVBLK=64: 8 chunks x 8 kv rows)
  const int krow_in = lane >> 3;
  const int kcol    = 8 * ((lane & 7) ^ (lane >> 3));
  const int v_d     = ((lane >> 3) & 3) * 16 + 8 * (lane & 1);
  const unsigned vtr_base = (unsigned)(size_t)Vsb + 8u*(unsigned)lane + 768u*(unsigned)hi;

  auto stage = [&](int bi, int tt){
    unsigned short* Kd = Ksb + (p*2 + bi)*4096;
    unsigned short* Vd = Vsb + (p*2 + bi)*4096;
    #pragma unroll
    for (int j=0;j<2;j++){
      const int ch = qw*2 + j;
      const int krow = tt*64 + ch*8 + krow_in;
      gload_lds16(Kg + (size_t)krow * rs + kcol, Kd + ch*512);
      const int vkv = tt*64 + (ch*2 + hi)*4 + ((lane>>1)&3);
      gload_lds16(Vg + (size_t)vkv * rs + v_d, Vd + ch*512);
    }
  };

  const int tmax = 2*qb + 1;
  stage(0, p);
  __syncthreads();
  int cur = 0;

  for (int t = p; t <= tmax; t += 2){
    if (t + 2 <= tmax) stage(cur^1, t+2);   // prefetch own next tile

    const char* Kb = (const char*)(Ksb + (p*2 + cur)*4096);
    const unsigned vb = vtr_base + (unsigned)((p*2 + cur)*8192);

    const int kv0 = t*64;
    const bool act0 = kv0 <= qw_hi;
    const bool act1 = kv0 + 32 <= qw_hi;

    if (act0 & act1){
      // ================= merged 64-kv step =================
      f32x16 S0, S1;
      #pragma unroll
      for (int r=0;r<16;r++){ S0[r]=0.f; S1[r]=0.f; }
      __builtin_amdgcn_s_setprio(1);
      #pragma unroll
      for (int c=0;c<4;c++){
        const int row0 = l31, row1 = 32 + l31;
        short8 kf0 = *(const short8*)(Kb + row0*128 + ((c*32 + 16*hi) ^ ((row0&7)<<4)));
        short8 kf1 = *(const short8*)(Kb + row1*128 + ((c*32 + 16*hi) ^ ((row1&7)<<4)));
        S0 = __builtin_amdgcn_mfma_f32_32x32x16_bf16(kf0, qf[c], S0, 0, 0, 0);
        S1 = __builtin_amdgcn_mfma_f32_32x32x16_bf16(kf1, qf[c], S1, 0, 0, 0);
      }
      __builtin_amdgcn_s_setprio(0);

      // batch 0: 8 tr-reads (kvs=0) — latency hides under the softmax
      int2v tva[8];
      #pragma unroll
      for (int c=0;c<2;c++)
        #pragma unroll
        for (int dh=0;dh<2;dh++)
          #pragma unroll
          for (int eb=0;eb<2;eb++)
            tva[c*4+dh*2+eb] = ds_tr_b16(vb + (unsigned)((c*4 + eb)*512 + dh*256));

      // ---- single softmax pass over 64 kv ----
      float mA=-1e30f, mB=-1e30f, mC=-1e30f, mD=-1e30f;
      if (kv0 + 31 > q0w){
        #pragma unroll
        for (int r=0;r<16;r+=4){
          const int kvb = kv0 + 8*(r>>2) + 4*hi;
          float s0 = (kvb+0 <= q) ? S0[r+0]*SC2 : -1e30f;
          float s1 = (kvb+1 <= q) ? S0[r+1]*SC2 : -1e30f;
          float s2 = (kvb+2 <= q) ? S0[r+2]*SC2 : -1e30f;
          float s3 = (kvb+3 <= q) ? S0[r+3]*SC2 : -1e30f;
          S0[r+0]=s0; S0[r+1]=s1; S0[r+2]=s2; S0[r+3]=s3;
          mA = fmaxf(mA, s0); mB = fmaxf(mB, s1); mC = fmaxf(mC, s2); mD = fmaxf(mD, s3);
        }
      } else {
        #pragma unroll
        for (int r=0;r<16;r+=4){
          float s0=S0[r+0]*SC2, s1=S0[r+1]*SC2, s2=S0[r+2]*SC2, s3=S0[r+3]*SC2;
          S0[r+0]=s0; S0[r+1]=s1; S0[r+2]=s2; S0[r+3]=s3;
          mA = fmaxf(mA, s0); mB = fmaxf(mB, s1); mC = fmaxf(mC, s2); mD = fmaxf(mD, s3);
        }
      }
      if (kv0 + 63 > q0w){
        #pragma unroll
        for (int r=0;r<16;r+=4){
          const int kvb = kv0 + 32 + 8*(r>>2) + 4*hi;
          float s0 = (kvb+0 <= q) ? S1[r+0]*SC2 : -1e30f;
          float s1 = (kvb+1 <= q) ? S1[r+1]*SC2 : -1e30f;
          float s2 = (kvb+2 <= q) ? S1[r+2]*SC2 : -1e30f;
          float s3 = (kvb+3 <= q) ? S1[r+3]*SC2 : -1e30f;
          S1[r+0]=s0; S1[r+1]=s1; S1[r+2]=s2; S1[r+3]=s3;
          mA = fmaxf(mA, s0); mB = fmaxf(mB, s1); mC = fmaxf(mC, s2); mD = fmaxf(mD, s3);
        }
      } else {
        #pragma unroll
        for (int r=0;r<16;r+=4){
          float s0=S1[r+0]*SC2, s1=S1[r+1]*SC2, s2=S1[r+2]*SC2, s3=S1[r+3]*SC2;
          S1[r+0]=s0; S1[r+1]=s1; S1[r+2]=s2; S1[r+3]=s3;
          mA = fmaxf(mA, s0); mB = fmaxf(mB, s1); mC = fmaxf(mC, s2); mD = fmaxf(mD, s3);
        }
      }
      float mx = fmaxf(fmaxf(mA,mB), fmaxf(mC,mD));
      mx = plmax(mx);

      if (!__all(mx <= m_run + 8.f)){
        const float m_new = fmaxf(m_run, mx);
        const float corr = __builtin_exp2f(m_run - m_new);
        m_run = m_new;
        l_run *= corr;
        #pragma unroll
        for (int r=0;r<16;r++){ O0[r] *= corr; O1[r] *= corr; }
      }

      float lA=0.f, lB=0.f, lC=0.f, lD=0.f;
      #pragma unroll
      for (int r=0;r<16;r+=4){
        float p0=__builtin_exp2f(S0[r+0]-m_run), p1=__builtin_exp2f(S0[r+1]-m_run);
        float p2=__builtin_exp2f(S0[r+2]-m_run), p3=__builtin_exp2f(S0[r+3]-m_run);
        S0[r+0]=p0; S0[r+1]=p1; S0[r+2]=p2; S0[r+3]=p3;
        lA+=p0; lB+=p1; lC+=p2; lD+=p3;
        float p4=__builtin_exp2f(S1[r+0]-m_run), p5=__builtin_exp2f(S1[r+1]-m_run);
        float p6=__builtin_exp2f(S1[r+2]-m_run), p7=__builtin_exp2f(S1[r+3]-m_run);
        S1[r+0]=p4; S1[r+1]=p5; S1[r+2]=p6; S1[r+3]=p7;
        lA+=p4; lB+=p5; lC+=p6; lD+=p7;
      }
      float ls = (lA+lB) + (lC+lD);
      ls = pladd(ls);
      l_run += ls;

      // ---- P^T -> bf16 fragments (both halves; S0/S1 die here) ----
      short8 pfrag[4];
      #pragma unroll
      for (int kvs=0;kvs<2;kvs++){
        unsigned pk[8];
        #pragma unroll
        for (int i=0;i<8;i++)
          pk[i] = kvs ? cvt_pk_bf16(S1[2*i], S1[2*i+1]) : cvt_pk_bf16(S0[2*i], S0[2*i+1]);
        #pragma unroll
        for (int c=0;c<2;c++){
          int2v r0 = plswap((int)pk[4*c+0], (int)pk[4*c+2]);
          int2v r1 = plswap((int)pk[4*c+1], (int)pk[4*c+3]);
          union { unsigned u[4]; short8 s; } pw;
          pw.u[0] = (unsigned)r0.x; pw.u[1] = (unsigned)r1.x;
          pw.u[2] = (unsigned)r0.y; pw.u[3] = (unsigned)r1.y;
          pfrag[kvs*2+c] = pw.s;
        }
      }

      // batch 1: 8 tr-reads (kvs=1) — latency hides under PV0
      int2v tvb[8];
      #pragma unroll
      for (int c=0;c<2;c++)
        #pragma unroll
        for (int dh=0;dh<2;dh++)
          #pragma unroll
          for (int eb=0;eb<2;eb++)
            tvb[c*4+dh*2+eb] = ds_tr_b16(vb + (unsigned)((8 + c*4 + eb)*512 + dh*256));

      asm volatile("s_waitcnt lgkmcnt(8)" ::: "memory");   // batch 0 complete (DS in-order)
      __builtin_amdgcn_sched_barrier(0);

      __builtin_amdgcn_s_setprio(1);
      #pragma unroll
      for (int c=0;c<2;c++){
        union { int2v t[2]; short8 s; } v0, v1;
        v0.t[0] = tva[c*4+0]; v0.t[1] = tva[c*4+1];
        v1.t[0] = tva[c*4+2]; v1.t[1] = tva[c*4+3];
        O0 = __builtin_amdgcn_mfma_f32_32x32x16_bf16(v0.s, pfrag[c], O0, 0, 0, 0);
        O1 = __builtin_amdgcn_mfma_f32_32x32x16_bf16(v1.s, pfrag[c], O1, 0, 0, 0);
      }
      __builtin_amdgcn_s_setprio(0);

      asm volatile("s_waitcnt lgkmcnt(0)" ::: "memory");   // batch 1 complete
      __builtin_amdgcn_sched_barrier(0);

      __builtin_amdgcn_s_setprio(1);
      #pragma unroll
      for (int c=0;c<2;c++){
        union { int2v t[2]; short8 s; } v0, v1;
        v0.t[0] = tvb[c*4+0]; v0.t[1] = tvb[c*4+1];
        v1.t[0] = tvb[c*4+2]; v1.t[1] = tvb[c*4+3];
        O0 = __builtin_amdgcn_mfma_f32_32x32x16_bf16(v0.s, pfrag[2+c], O0, 0, 0, 0);
        O1 = __builtin_amdgcn_mfma_f32_32x32x16_bf16(v1.s, pfrag[2+c], O1, 0, 0, 0);
      }
      __builtin_amdgcn_s_setprio(0);

    } else if (act0){
      // ================= single 32-kv step (diag tail; R8-verified) =================
      f32x16 S;
      #pragma unroll
      for (int r=0;r<16;r++) S[r] = 0.f;
      __builtin_amdgcn_s_setprio(1);
      #pragma unroll
      for (int c=0;c<4;c++){
        const int row = l31;
        short8 kf = *(const short8*)(Kb + row*128 + ((c*32 + 16*hi) ^ ((row&7)<<4)));
        S = __builtin_amdgcn_mfma_f32_32x32x16_bf16(kf, qf[c], S, 0, 0, 0);
      }
      __builtin_amdgcn_s_setprio(0);

      int2v tv[8];
      #pragma unroll
      for (int c=0;c<2;c++)
        #pragma unroll
        for (int dh=0;dh<2;dh++)
          #pragma unroll
          for (int eb=0;eb<2;eb++)
            tv[c*4+dh*2+eb] = ds_tr_b16(vb + (unsigned)((c*4 + eb)*512 + dh*256));

      float mA=-1e30f, mB=-1e30f, mC=-1e30f, mD=-1e30f;
      if (kv0 + 31 > q0w){
        #pragma unroll
        for (int r=0;r<16;r+=4){
          const int kvb = kv0 + 8*(r>>2) + 4*hi;
          float s0 = (kvb+0 <= q) ? S[r+0]*SC2 : -1e30f;
          float s1 = (kvb+1 <= q) ? S[r+1]*SC2 : -1e30f;
          float s2 = (kvb+2 <= q) ? S[r+2]*SC2 : -1e30f;
          float s3 = (kvb+3 <= q) ? S[r+3]*SC2 : -1e30f;
          S[r+0]=s0; S[r+1]=s1; S[r+2]=s2; S[r+3]=s3;
          mA = fmaxf(mA, s0); mB = fmaxf(mB, s1); mC = fmaxf(mC, s2); mD = fmaxf(mD, s3);
        }
      } else {
        #pragma unroll
        for (int r=0;r<16;r+=4){
          float s0=S[r+0]*SC2, s1=S[r+1]*SC2, s2=S[r+2]*SC2, s3=S[r+3]*SC2;
          S[r+0]=s0; S[r+1]=s1; S[r+2]=s2; S[r+3]=s3;
          mA = fmaxf(mA, s0); mB = fmaxf(mB, s1); mC = fmaxf(mC, s2); mD = fmaxf(mD, s3);
        }
      }
      float mx = fmaxf(fmaxf(mA,mB), fmaxf(mC,mD));
      mx = plmax(mx);

      if (!__all(mx <= m_run + 8.f)){
        const float m_new = fmaxf(m_run, mx);
        const float corr = __builtin_exp2f(m_run - m_new);
        m_run = m_new;
        l_run *= corr;
        #pragma unroll
        for (int r=0;r<16;r++){ O0[r] *= corr; O1[r] *= corr; }
      }

      float lA=0.f, lB=0.f, lC=0.f, lD=0.f;
      #pragma unroll
      for (int r=0;r<16;r+=4){
        float p0=__builtin_exp2f(S[r+0]-m_run), p1=__builtin_exp2f(S[r+1]-m_run);
        float p2=__builtin_exp2f(S[r+2]-m_run), p3=__builtin_exp2f(S[r+3]-m_run);
        S[r+0]=p0; S[r+1]=p1; S[r+2]=p2; S[r+3]=p3;
        lA+=p0; lB+=p1; lC+=p2; lD+=p3;
      }
      float ls = (lA+lB) + (lC+lD);
      ls = pladd(ls);
      l_run += ls;

      unsigned pk[8];
      #pragma unroll
      for (int i=0;i<8;i++) pk[i] = cvt_pk_bf16(S[2*i], S[2*i+1]);
      short8 pfrag[2];
      #pragma unroll
      for (int c=0;c<2;c++){
        int2v r0 = plswap((int)pk[4*c+0], (int)pk[4*c+2]);
        int2v r1 = plswap((int)pk[4*c+1], (int)pk[4*c+3]);
        union { unsigned u[4]; short8 s; } pw;
        pw.u[0] = (unsigned)r0.x; pw.u[1] = (unsigned)r1.x;
        pw.u[2] = (unsigned)r0.y; pw.u[3] = (unsigned)r1.y;
        pfrag[c] = pw.s;
      }

      asm volatile("s_waitcnt lgkmcnt(0)" ::: "memory");
      __builtin_amdgcn_sched_barrier(0);

      __builtin_amdgcn_s_setprio(1);
      #pragma unroll
      for (int c=0;c<2;c++){
        union { int2v t[2]; short8 s; } v0, v1;
        v0.t[0] = tv[c*4+0]; v0.t[1] = tv[c*4+1];
        v1.t[0] = tv[c*4+2]; v1.t[1] = tv[c*4+3];
        O0 = __builtin_amdgcn_mfma_f32_32x32x16_bf16(v0.s, pfrag[c], O0, 0, 0, 0);
        O1 = __builtin_amdgcn_mfma_f32_32x32x16_bf16(v1.s, pfrag[c], O1, 0, 0, 0);
      }
      __builtin_amdgcn_s_setprio(0);
    }

    __syncthreads();   // drains prefetch (vmcnt) + protects buffer reuse
    cur ^= 1;
  }

  // ---- merge parity partials (p=1 -> LDS, p=0 merges + writes) ----
  float* sm = (float*)lds + qw * (64*34);
  if (p){
    #pragma unroll
    for (int r=0;r<16;r++){ sm[lane*34 + r] = O0[r]; sm[lane*34 + 16 + r] = O1[r]; }
    sm[lane*34 + 32] = m_run;
    sm[lane*34 + 33] = l_run;
  }
  __syncthreads();
  if (!p){
    const float m1 = sm[lane*34 + 32], l1 = sm[lane*34 + 33];
    const float mm = fmaxf(m_run, m1);
    const float c0 = __builtin_exp2f(m_run - mm);
    const float c1 = __builtin_exp2f(m1 - mm);
    const float inv = 1.f / (l_run*c0 + l1*c1);
    unsigned short* dst = aout + ((size_t)b*SS + q) * NXDIM + h*HDIM;
    #pragma unroll
    for (int g4=0; g4<4; g4++){
      ushort4v a0, a1;
      #pragma unroll
      for (int i=0;i<4;i++){
        a0[i] = f2bf((O0[4*g4+i]*c0 + sm[lane*34 + 4*g4+i]*c1) * inv);
        a1[i] = f2bf((O1[4*g4+i]*c0 + sm[lane*34 + 16 + 4*g4+i]*c1) * inv);
      }
      *(ushort4v*)(dst + 8*g4 + 4*hi)      = a0;
      *(ushort4v*)(dst + 32 + 8*g4 + 4*hi) = a1;
    }
  }
}

extern "C" void kernel_launch(void* const* d_in, const int* in_sizes, int n_in,
                              void* d_out, int out_size, void* d_ws, size_t ws_size,
                              hipStream_t stream){
  (void)in_sizes; (void)n_in; (void)out_size; (void)ws_size;
  const float* x      = (const float*)d_in[0];   // [2,2048,1024]
  const float* w_attn = (const float*)d_in[1];   // [1024,3072]
  const float* b_attn = (const float*)d_in[2];   // [3072]
  const float* w_proj = (const float*)d_in[3];   // [1024,1024]
  const float* b_proj = (const float*)d_in[4];   // [1024]
  float* out = (float*)d_out;                    // [2,2048,1024] f32

  unsigned short* xb   = (unsigned short*)d_ws;              // 4096x1024 bf16
  unsigned short* waT  = xb  + (size_t)4096*1024;            // 3072x1024 bf16 (W_attn^T)
  unsigned short* wpT  = waT + (size_t)3072*1024;            // 1024x1024 bf16 (W_proj^T)
  unsigned short* qkv  = wpT + (size_t)1024*1024;            // 4096x3072 bf16
  unsigned short* aout = qkv + (size_t)4096*3072;            // 4096x1024 bf16

  f32_to_bf16_k<<<4096, 256, 0, stream>>>(x, xb, 4096*1024/4);
  transpose_bf16_k<<<dim3(3072/32, 1024/32), dim3(32,8), 0, stream>>>(w_attn, waT, 1024, 3072);
  transpose_bf16_k<<<dim3(1024/32, 1024/32), dim3(32,8), 0, stream>>>(w_proj, wpT, 1024, 1024);

  gemm_bt_k<false><<<dim3(3072/128, 4096/128), 256, 0, stream>>>(xb, waT, b_attn, (void*)qkv, 4096, 3072, 1024);
  attn_k<<<dim3(SS/128, NHEADS, BB), 512, 0, stream>>>(qkv, aout);
  gemm_bt_k<true><<<dim3(1024/128, 4096/128), 256, 0, stream>>>(aout, wpT, b_proj, (void*)out, 4096, 1024, 1024);
}

// Round 11
// 147.202 us; speedup vs baseline: 1.3098x; 1.0734x over previous
//
#include <hip/hip_runtime.h>
#include <stdint.h>

typedef __attribute__((ext_vector_type(8))) short short8;
typedef __attribute__((ext_vector_type(4))) float f32x4;
typedef __attribute__((ext_vector_type(16))) float f32x16;
typedef __attribute__((ext_vector_type(4))) unsigned short ushort4v;
typedef __attribute__((ext_vector_type(2))) int int2v;

#define BB 2
#define SS 2048
#define NXDIM 1024
#define NHEADS 16
#define HDIM 64

__device__ __forceinline__ unsigned short f2bf(float f){
  unsigned int u = __float_as_uint(f);
  u += 0x7fffu + ((u >> 16) & 1u);
  return (unsigned short)(u >> 16);
}

__device__ __forceinline__ void gload_lds16(const void* g, void* l){
  __builtin_amdgcn_global_load_lds((const __attribute__((address_space(1))) void*)g,
                                   (__attribute__((address_space(3))) void*)l, 16, 0, 0);
}

__device__ __forceinline__ unsigned cvt_pk_bf16(float lo, float hi){
  unsigned r;
  asm("v_cvt_pk_bf16_f32 %0, %1, %2" : "=v"(r) : "v"(lo), "v"(hi));
  return r;
}

__device__ __forceinline__ int2v ds_tr_b16(unsigned addr){
  int2v r;
  asm volatile("ds_read_b64_tr_b16 %0, %1" : "=v"(r) : "v"(addr));
  return r;
}

// permlane32_swap (SSA builtin, no operand aliasing)
__device__ __forceinline__ int2v plswap(int a, int b){
  return __builtin_amdgcn_permlane32_swap(a, b, false, false);
}
__device__ __forceinline__ float plmax(float x){
  int2v r = plswap(__float_as_int(x), __float_as_int(x));
  return fmaxf(__int_as_float(r.x), __int_as_float(r.y));
}
__device__ __forceinline__ float pladd(float x){
  int2v r = plswap(__float_as_int(x), __float_as_int(x));
  return __int_as_float(r.x) + __int_as_float(r.y);
}

// ---------------- f32 -> bf16 convert (vectorized) ----------------
__global__ __launch_bounds__(256) void f32_to_bf16_k(const float* __restrict__ in,
                                                     unsigned short* __restrict__ out, int n4){
  int i = blockIdx.x * 256 + threadIdx.x;
  if (i >= n4) return;
  float4 v = ((const float4*)in)[i];
  ushort4v r = { f2bf(v.x), f2bf(v.y), f2bf(v.z), f2bf(v.w) };
  ((ushort4v*)out)[i] = r;
}

// ---------------- f32 [R][C] -> bf16 transposed [C][R] ----------------
__global__ __launch_bounds__(256) void transpose_bf16_k(const float* __restrict__ in,
                                                        unsigned short* __restrict__ out,
                                                        int R, int C){
  __shared__ float t[32][33];
  const int bx = blockIdx.x * 32, by = blockIdx.y * 32;
  const int tx = threadIdx.x, ty = threadIdx.y;
  #pragma unroll
  for (int i = ty; i < 32; i += 8)
    t[i][tx] = in[(size_t)(by + i) * C + bx + tx];
  __syncthreads();
  #pragma unroll
  for (int i = ty; i < 32; i += 8)
    out[(size_t)(bx + i) * R + by + tx] = f2bf(t[tx][i]);
}

// ---------------- bf16 GEMM: C[M,N] = A[M,K] * BT[N,K]^T + bias ----------------
template<bool OUT_F32>
__global__ __launch_bounds__(256) void gemm_bt_k(const unsigned short* __restrict__ A,
                                                 const unsigned short* __restrict__ BT,
                                                 const float* __restrict__ bias,
                                                 void* __restrict__ Cout,
                                                 int M, int N, int K)
{
  __shared__ unsigned short As[128*32];
  __shared__ unsigned short Bs[128*32];
  const int tid = threadIdx.x;
  const int w = tid >> 6, lane = tid & 63;
  const int l15 = lane & 15, g = lane >> 4;
  const int wr = w >> 1, wc = w & 1;
  const int m0 = blockIdx.y * 128, n0 = blockIdx.x * 128;

  f32x4 acc[4][4];
  #pragma unroll
  for (int m=0;m<4;m++)
    #pragma unroll
    for (int n=0;n<4;n++) acc[m][n] = (f32x4){0.f,0.f,0.f,0.f};

  const int scol = (lane & 3) * 8;

  for (int k0 = 0; k0 < K; k0 += 32){
    __syncthreads();
    #pragma unroll
    for (int j=0;j<2;j++){
      const int row = w*32 + j*16 + (lane >> 2);
      const unsigned short* ga = A  + (size_t)(m0 + row) * K + (k0 + scol);
      const unsigned short* gb = BT + (size_t)(n0 + row) * K + (k0 + scol);
      gload_lds16(ga, &As[(w*32 + j*16) * 32]);
      gload_lds16(gb, &Bs[(w*32 + j*16) * 32]);
    }
    __syncthreads();

    short8 af[4], bf[4];
    #pragma unroll
    for (int m=0;m<4;m++) af[m] = *(const short8*)&As[(wr*64 + m*16 + l15)*32 + g*8];
    #pragma unroll
    for (int n=0;n<4;n++) bf[n] = *(const short8*)&Bs[(wc*64 + n*16 + l15)*32 + g*8];
    #pragma unroll
    for (int m=0;m<4;m++)
      #pragma unroll
      for (int n=0;n<4;n++)
        acc[m][n] = __builtin_amdgcn_mfma_f32_16x16x32_bf16(af[m], bf[n], acc[m][n], 0, 0, 0);
  }

  const int crow0 = m0 + wr*64;
  const int ccol0 = n0 + wc*64;
  #pragma unroll
  for (int n=0;n<4;n++){
    const int col = ccol0 + n*16 + l15;
    const float bv = bias[col];
    #pragma unroll
    for (int m=0;m<4;m++){
      #pragma unroll
      for (int r=0;r<4;r++){
        const int row = crow0 + m*16 + g*4 + r;
        const float v = acc[m][n][r] + bv;
        if (OUT_F32) ((float*)Cout)[(size_t)row * N + col] = v;
        else         ((unsigned short*)Cout)[(size_t)row * N + col] = f2bf(v);
      }
    }
  }
}

// ---------------- causal flash attention, swapped-operand 32x32 MFMA ----------------
// 512 threads = 8 waves = 4 q-waves x 2 kv-parities (R7-R10-verified structure).
// NEW: CU-load-balanced qb map (co-resident z=0/z=1 blocks get complementary qb),
// raw-domain softmax (scale folded into exp via FMA; gate threshold 8/SC2).
__global__ __launch_bounds__(512) void attn_k(const unsigned short* __restrict__ qkv,
                                              unsigned short* __restrict__ aout)
{
  // complementary pairing: blocks (x,y,0) and (x,y,1) land on the same CU slot
  // (x-fastest dispatch, 2 blocks/CU); give them qb and 15-qb -> pair sum const.
  const int xy = ((int)blockIdx.x + (int)blockIdx.y) & 15;
  const int qb = blockIdx.z ? xy : (15 - xy);
  const int h = blockIdx.y, b = blockIdx.z;
  const int tid = threadIdx.x;
  const int w = tid >> 6, lane = tid & 63;
  const int l31 = lane & 31, hi = lane >> 5;
  const int qw = w >> 1, p = w & 1;

  __shared__ unsigned short lds[32768];              // 64 KB
  unsigned short* Ksb = lds;                         // [par][buf][64*64] K, XOR-swizzled rows
  unsigned short* Vsb = lds + 16384;                 // [par][buf][64*64] V, tr_b16 subtiled

  const size_t rs = 3 * NXDIM;
  const unsigned short* Qg = qkv + (size_t)b * SS * rs + h * HDIM;
  const unsigned short* Kg = Qg + NXDIM;
  const unsigned short* Vg = Qg + 2 * NXDIM;

  const int q0w = qb*128 + qw*32;
  const int q   = q0w + l31;
  const int qw_hi = q0w + 31;

  short8 qf[4];
  #pragma unroll
  for (int c=0;c<4;c++)
    qf[c] = *(const short8*)(Qg + (size_t)q * rs + c*16 + 8*hi);

  f32x16 O0, O1;
  #pragma unroll
  for (int r=0;r<16;r++){ O0[r]=0.f; O1[r]=0.f; }
  float m_run = -1e30f, l_run = 0.f;         // m_run in RAW score domain
  const float SC2 = 0.125f * 1.44269504089f; // scale * log2(e)
  const float THRR = 44.36f;                 // 8 / SC2 (defer threshold, raw domain)

  // staging source coords (R4-verified maps, KVBLK=64: 8 chunks x 8 kv rows)
  const int krow_in = lane >> 3;
  const int kcol    = 8 * ((lane & 7) ^ (lane >> 3));
  const int v_d     = ((lane >> 3) & 3) * 16 + 8 * (lane & 1);
  const unsigned vtr_base = (unsigned)(size_t)Vsb + 8u*(unsigned)lane + 768u*(unsigned)hi;

  auto stage = [&](int bi, int tt){
    unsigned short* Kd = Ksb + (p*2 + bi)*4096;
    unsigned short* Vd = Vsb + (p*2 + bi)*4096;
    #pragma unroll
    for (int j=0;j<2;j++){
      const int ch = qw*2 + j;
      const int krow = tt*64 + ch*8 + krow_in;
      gload_lds16(Kg + (size_t)krow * rs + kcol, Kd + ch*512);
      const int vkv = tt*64 + (ch*2 + hi)*4 + ((lane>>1)&3);
      gload_lds16(Vg + (size_t)vkv * rs + v_d, Vd + ch*512);
    }
  };

  const int tmax = 2*qb + 1;
  stage(0, p);
  __syncthreads();
  int cur = 0;

  for (int t = p; t <= tmax; t += 2){
    if (t + 2 <= tmax) stage(cur^1, t+2);   // prefetch own next tile

    const char* Kb = (const char*)(Ksb + (p*2 + cur)*4096);
    const unsigned vb = vtr_base + (unsigned)((p*2 + cur)*8192);

    const int kv0 = t*64;
    const bool act0 = kv0 <= qw_hi;
    const bool act1 = kv0 + 32 <= qw_hi;

    if (act0 & act1){
      // ================= merged 64-kv step =================
      f32x16 S0, S1;
      #pragma unroll
      for (int r=0;r<16;r++){ S0[r]=0.f; S1[r]=0.f; }
      __builtin_amdgcn_s_setprio(1);
      #pragma unroll
      for (int c=0;c<4;c++){
        const int row0 = l31, row1 = 32 + l31;
        short8 kf0 = *(const short8*)(Kb + row0*128 + ((c*32 + 16*hi) ^ ((row0&7)<<4)));
        short8 kf1 = *(const short8*)(Kb + row1*128 + ((c*32 + 16*hi) ^ ((row1&7)<<4)));
        S0 = __builtin_amdgcn_mfma_f32_32x32x16_bf16(kf0, qf[c], S0, 0, 0, 0);
        S1 = __builtin_amdgcn_mfma_f32_32x32x16_bf16(kf1, qf[c], S1, 0, 0, 0);
      }
      __builtin_amdgcn_s_setprio(0);

      // batch 0: 8 tr-reads (kvs=0) — latency hides under the softmax
      int2v tva[8];
      #pragma unroll
      for (int c=0;c<2;c++)
        #pragma unroll
        for (int dh=0;dh<2;dh++)
          #pragma unroll
          for (int eb=0;eb<2;eb++)
            tva[c*4+dh*2+eb] = ds_tr_b16(vb + (unsigned)((c*4 + eb)*512 + dh*256));

      // ---- single softmax pass over 64 kv (raw domain) ----
      float mA=-1e30f, mB=-1e30f, mC=-1e30f, mD=-1e30f;
      if (kv0 + 31 > q0w){
        #pragma unroll
        for (int r=0;r<16;r+=4){
          const int kvb = kv0 + 8*(r>>2) + 4*hi;
          float s0 = (kvb+0 <= q) ? S0[r+0] : -1e30f;
          float s1 = (kvb+1 <= q) ? S0[r+1] : -1e30f;
          float s2 = (kvb+2 <= q) ? S0[r+2] : -1e30f;
          float s3 = (kvb+3 <= q) ? S0[r+3] : -1e30f;
          S0[r+0]=s0; S0[r+1]=s1; S0[r+2]=s2; S0[r+3]=s3;
          mA = fmaxf(mA, s0); mB = fmaxf(mB, s1); mC = fmaxf(mC, s2); mD = fmaxf(mD, s3);
        }
      } else {
        #pragma unroll
        for (int r=0;r<16;r+=4){
          mA = fmaxf(mA, S0[r+0]); mB = fmaxf(mB, S0[r+1]);
          mC = fmaxf(mC, S0[r+2]); mD = fmaxf(mD, S0[r+3]);
        }
      }
      if (kv0 + 63 > q0w){
        #pragma unroll
        for (int r=0;r<16;r+=4){
          const int kvb = kv0 + 32 + 8*(r>>2) + 4*hi;
          float s0 = (kvb+0 <= q) ? S1[r+0] : -1e30f;
          float s1 = (kvb+1 <= q) ? S1[r+1] : -1e30f;
          float s2 = (kvb+2 <= q) ? S1[r+2] : -1e30f;
          float s3 = (kvb+3 <= q) ? S1[r+3] : -1e30f;
          S1[r+0]=s0; S1[r+1]=s1; S1[r+2]=s2; S1[r+3]=s3;
          mA = fmaxf(mA, s0); mB = fmaxf(mB, s1); mC = fmaxf(mC, s2); mD = fmaxf(mD, s3);
        }
      } else {
        #pragma unroll
        for (int r=0;r<16;r+=4){
          mA = fmaxf(mA, S1[r+0]); mB = fmaxf(mB, S1[r+1]);
          mC = fmaxf(mC, S1[r+2]); mD = fmaxf(mD, S1[r+3]);
        }
      }
      float mx = fmaxf(fmaxf(mA,mB), fmaxf(mC,mD));
      mx = plmax(mx);

      if (!__all(mx <= m_run + THRR)){
        const float m_new = fmaxf(m_run, mx);
        const float corr = __builtin_exp2f((m_run - m_new) * SC2);
        m_run = m_new;
        l_run *= corr;
        #pragma unroll
        for (int r=0;r<16;r++){ O0[r] *= corr; O1[r] *= corr; }
      }
      const float msc = m_run * SC2;

      float lA=0.f, lB=0.f, lC=0.f, lD=0.f;
      #pragma unroll
      for (int r=0;r<16;r+=4){
        float p0=__builtin_exp2f(__builtin_fmaf(S0[r+0],SC2,-msc));
        float p1=__builtin_exp2f(__builtin_fmaf(S0[r+1],SC2,-msc));
        float p2=__builtin_exp2f(__builtin_fmaf(S0[r+2],SC2,-msc));
        float p3=__builtin_exp2f(__builtin_fmaf(S0[r+3],SC2,-msc));
        S0[r+0]=p0; S0[r+1]=p1; S0[r+2]=p2; S0[r+3]=p3;
        lA+=p0; lB+=p1; lC+=p2; lD+=p3;
        float p4=__builtin_exp2f(__builtin_fmaf(S1[r+0],SC2,-msc));
        float p5=__builtin_exp2f(__builtin_fmaf(S1[r+1],SC2,-msc));
        float p6=__builtin_exp2f(__builtin_fmaf(S1[r+2],SC2,-msc));
        float p7=__builtin_exp2f(__builtin_fmaf(S1[r+3],SC2,-msc));
        S1[r+0]=p4; S1[r+1]=p5; S1[r+2]=p6; S1[r+3]=p7;
        lA+=p4; lB+=p5; lC+=p6; lD+=p7;
      }
      float ls = (lA+lB) + (lC+lD);
      ls = pladd(ls);
      l_run += ls;

      // ---- P^T -> bf16 fragments (both halves; S0/S1 die here) ----
      short8 pfrag[4];
      #pragma unroll
      for (int kvs=0;kvs<2;kvs++){
        unsigned pk[8];
        #pragma unroll
        for (int i=0;i<8;i++)
          pk[i] = kvs ? cvt_pk_bf16(S1[2*i], S1[2*i+1]) : cvt_pk_bf16(S0[2*i], S0[2*i+1]);
        #pragma unroll
        for (int c=0;c<2;c++){
          int2v r0 = plswap((int)pk[4*c+0], (int)pk[4*c+2]);
          int2v r1 = plswap((int)pk[4*c+1], (int)pk[4*c+3]);
          union { unsigned u[4]; short8 s; } pw;
          pw.u[0] = (unsigned)r0.x; pw.u[1] = (unsigned)r1.x;
          pw.u[2] = (unsigned)r0.y; pw.u[3] = (unsigned)r1.y;
          pfrag[kvs*2+c] = pw.s;
        }
      }

      // batch 1: 8 tr-reads (kvs=1) — latency hides under PV0
      int2v tvb[8];
      #pragma unroll
      for (int c=0;c<2;c++)
        #pragma unroll
        for (int dh=0;dh<2;dh++)
          #pragma unroll
          for (int eb=0;eb<2;eb++)
            tvb[c*4+dh*2+eb] = ds_tr_b16(vb + (unsigned)((8 + c*4 + eb)*512 + dh*256));

      asm volatile("s_waitcnt lgkmcnt(8)" ::: "memory");   // batch 0 complete (DS in-order)
      __builtin_amdgcn_sched_barrier(0);

      __builtin_amdgcn_s_setprio(1);
      #pragma unroll
      for (int c=0;c<2;c++){
        union { int2v t[2]; short8 s; } v0, v1;
        v0.t[0] = tva[c*4+0]; v0.t[1] = tva[c*4+1];
        v1.t[0] = tva[c*4+2]; v1.t[1] = tva[c*4+3];
        O0 = __builtin_amdgcn_mfma_f32_32x32x16_bf16(v0.s, pfrag[c], O0, 0, 0, 0);
        O1 = __builtin_amdgcn_mfma_f32_32x32x16_bf16(v1.s, pfrag[c], O1, 0, 0, 0);
      }
      __builtin_amdgcn_s_setprio(0);

      asm volatile("s_waitcnt lgkmcnt(0)" ::: "memory");   // batch 1 complete
      __builtin_amdgcn_sched_barrier(0);

      __builtin_amdgcn_s_setprio(1);
      #pragma unroll
      for (int c=0;c<2;c++){
        union { int2v t[2]; short8 s; } v0, v1;
        v0.t[0] = tvb[c*4+0]; v0.t[1] = tvb[c*4+1];
        v1.t[0] = tvb[c*4+2]; v1.t[1] = tvb[c*4+3];
        O0 = __builtin_amdgcn_mfma_f32_32x32x16_bf16(v0.s, pfrag[2+c], O0, 0, 0, 0);
        O1 = __builtin_amdgcn_mfma_f32_32x32x16_bf16(v1.s, pfrag[2+c], O1, 0, 0, 0);
      }
      __builtin_amdgcn_s_setprio(0);

    } else if (act0){
      // ================= single 32-kv step (diag tail) =================
      f32x16 S;
      #pragma unroll
      for (int r=0;r<16;r++) S[r] = 0.f;
      __builtin_amdgcn_s_setprio(1);
      #pragma unroll
      for (int c=0;c<4;c++){
        const int row = l31;
        short8 kf = *(const short8*)(Kb + row*128 + ((c*32 + 16*hi) ^ ((row&7)<<4)));
        S = __builtin_amdgcn_mfma_f32_32x32x16_bf16(kf, qf[c], S, 0, 0, 0);
      }
      __builtin_amdgcn_s_setprio(0);

      int2v tv[8];
      #pragma unroll
      for (int c=0;c<2;c++)
        #pragma unroll
        for (int dh=0;dh<2;dh++)
          #pragma unroll
          for (int eb=0;eb<2;eb++)
            tv[c*4+dh*2+eb] = ds_tr_b16(vb + (unsigned)((c*4 + eb)*512 + dh*256));

      float mA=-1e30f, mB=-1e30f, mC=-1e30f, mD=-1e30f;
      if (kv0 + 31 > q0w){
        #pragma unroll
        for (int r=0;r<16;r+=4){
          const int kvb = kv0 + 8*(r>>2) + 4*hi;
          float s0 = (kvb+0 <= q) ? S[r+0] : -1e30f;
          float s1 = (kvb+1 <= q) ? S[r+1] : -1e30f;
          float s2 = (kvb+2 <= q) ? S[r+2] : -1e30f;
          float s3 = (kvb+3 <= q) ? S[r+3] : -1e30f;
          S[r+0]=s0; S[r+1]=s1; S[r+2]=s2; S[r+3]=s3;
          mA = fmaxf(mA, s0); mB = fmaxf(mB, s1); mC = fmaxf(mC, s2); mD = fmaxf(mD, s3);
        }
      } else {
        #pragma unroll
        for (int r=0;r<16;r+=4){
          mA = fmaxf(mA, S[r+0]); mB = fmaxf(mB, S[r+1]);
          mC = fmaxf(mC, S[r+2]); mD = fmaxf(mD, S[r+3]);
        }
      }
      float mx = fmaxf(fmaxf(mA,mB), fmaxf(mC,mD));
      mx = plmax(mx);

      if (!__all(mx <= m_run + THRR)){
        const float m_new = fmaxf(m_run, mx);
        const float corr = __builtin_exp2f((m_run - m_new) * SC2);
        m_run = m_new;
        l_run *= corr;
        #pragma unroll
        for (int r=0;r<16;r++){ O0[r] *= corr; O1[r] *= corr; }
      }
      const float msc = m_run * SC2;

      float lA=0.f, lB=0.f, lC=0.f, lD=0.f;
      #pragma unroll
      for (int r=0;r<16;r+=4){
        float p0=__builtin_exp2f(__builtin_fmaf(S[r+0],SC2,-msc));
        float p1=__builtin_exp2f(__builtin_fmaf(S[r+1],SC2,-msc));
        float p2=__builtin_exp2f(__builtin_fmaf(S[r+2],SC2,-msc));
        float p3=__builtin_exp2f(__builtin_fmaf(S[r+3],SC2,-msc));
        S[r+0]=p0; S[r+1]=p1; S[r+2]=p2; S[r+3]=p3;
        lA+=p0; lB+=p1; lC+=p2; lD+=p3;
      }
      float ls = (lA+lB) + (lC+lD);
      ls = pladd(ls);
      l_run += ls;

      unsigned pk[8];
      #pragma unroll
      for (int i=0;i<8;i++) pk[i] = cvt_pk_bf16(S[2*i], S[2*i+1]);
      short8 pfrag[2];
      #pragma unroll
      for (int c=0;c<2;c++){
        int2v r0 = plswap((int)pk[4*c+0], (int)pk[4*c+2]);
        int2v r1 = plswap((int)pk[4*c+1], (int)pk[4*c+3]);
        union { unsigned u[4]; short8 s; } pw;
        pw.u[0] = (unsigned)r0.x; pw.u[1] = (unsigned)r1.x;
        pw.u[2] = (unsigned)r0.y; pw.u[3] = (unsigned)r1.y;
        pfrag[c] = pw.s;
      }

      asm volatile("s_waitcnt lgkmcnt(0)" ::: "memory");
      __builtin_amdgcn_sched_barrier(0);

      __builtin_amdgcn_s_setprio(1);
      #pragma unroll
      for (int c=0;c<2;c++){
        union { int2v t[2]; short8 s; } v0, v1;
        v0.t[0] = tv[c*4+0]; v0.t[1] = tv[c*4+1];
        v1.t[0] = tv[c*4+2]; v1.t[1] = tv[c*4+3];
        O0 = __builtin_amdgcn_mfma_f32_32x32x16_bf16(v0.s, pfrag[c], O0, 0, 0, 0);
        O1 = __builtin_amdgcn_mfma_f32_32x32x16_bf16(v1.s, pfrag[c], O1, 0, 0, 0);
      }
      __builtin_amdgcn_s_setprio(0);
    }

    __syncthreads();   // drains prefetch (vmcnt) + protects buffer reuse
    cur ^= 1;
  }

  // ---- merge parity partials (p=1 -> LDS, p=0 merges + writes) ----
  float* sm = (float*)lds + qw * (64*34);
  if (p){
    #pragma unroll
    for (int r=0;r<16;r++){ sm[lane*34 + r] = O0[r]; sm[lane*34 + 16 + r] = O1[r]; }
    sm[lane*34 + 32] = m_run;
    sm[lane*34 + 33] = l_run;
  }
  __syncthreads();
  if (!p){
    const float m1 = sm[lane*34 + 32], l1 = sm[lane*34 + 33];
    const float mm = fmaxf(m_run, m1);
    const float c0 = __builtin_exp2f((m_run - mm) * SC2);
    const float c1 = __builtin_exp2f((m1 - mm) * SC2);
    const float inv = 1.f / (l_run*c0 + l1*c1);
    unsigned short* dst = aout + ((size_t)b*SS + q) * NXDIM + h*HDIM;
    #pragma unroll
    for (int g4=0; g4<4; g4++){
      ushort4v a0, a1;
      #pragma unroll
      for (int i=0;i<4;i++){
        a0[i] = f2bf((O0[4*g4+i]*c0 + sm[lane*34 + 4*g4+i]*c1) * inv);
        a1[i] = f2bf((O1[4*g4+i]*c0 + sm[lane*34 + 16 + 4*g4+i]*c1) * inv);
      }
      *(ushort4v*)(dst + 8*g4 + 4*hi)      = a0;
      *(ushort4v*)(dst + 32 + 8*g4 + 4*hi) = a1;
    }
  }
}

extern "C" void kernel_launch(void* const* d_in, const int* in_sizes, int n_in,
                              void* d_out, int out_size, void* d_ws, size_t ws_size,
                              hipStream_t stream){
  (void)in_sizes; (void)n_in; (void)out_size; (void)ws_size;
  const float* x      = (const float*)d_in[0];   // [2,2048,1024]
  const float* w_attn = (const float*)d_in[1];   // [1024,3072]
  const float* b_attn = (const float*)d_in[2];   // [3072]
  const float* w_proj = (const float*)d_in[3];   // [1024,1024]
  const float* b_proj = (const float*)d_in[4];   // [1024]
  float* out = (float*)d_out;                    // [2,2048,1024] f32

  unsigned short* xb   = (unsigned short*)d_ws;              // 4096x1024 bf16
  unsigned short* waT  = xb  + (size_t)4096*1024;            // 3072x1024 bf16 (W_attn^T)
  unsigned short* wpT  = waT + (size_t)3072*1024;            // 1024x1024 bf16 (W_proj^T)
  unsigned short* qkv  = wpT + (size_t)1024*1024;            // 4096x3072 bf16
  unsigned short* aout = qkv + (size_t)4096*3072;            // 4096x1024 bf16

  f32_to_bf16_k<<<4096, 256, 0, stream>>>(x, xb, 4096*1024/4);
  transpose_bf16_k<<<dim3(3072/32, 1024/32), dim3(32,8), 0, stream>>>(w_attn, waT, 1024, 3072);
  transpose_bf16_k<<<dim3(1024/32, 1024/32), dim3(32,8), 0, stream>>>(w_proj, wpT, 1024, 1024);

  gemm_bt_k<false><<<dim3(3072/128, 4096/128), 256, 0, stream>>>(xb, waT, b_attn, (void*)qkv, 4096, 3072, 1024);
  attn_k<<<dim3(SS/128, NHEADS, BB), 512, 0, stream>>>(qkv, aout);
  gemm_bt_k<true><<<dim3(1024/128, 4096/128), 256, 0, stream>>>(aout, wpT, b_proj, (void*)out, 4096, 1024, 1024);
}